// Round 6
// baseline (535.090 us; speedup 1.0000x reference)
//
#include <hip/hip_runtime.h>

#define N_NODES 100000
#define NE 500000
#define NEP 100000
#define NBLK_SCAN ((N_NODES + 255) / 256)   // 391

typedef short bf16x8 __attribute__((ext_vector_type(8)));
typedef float f32x4  __attribute__((ext_vector_type(4)));
typedef ushort ushort8v __attribute__((ext_vector_type(8)));

__device__ inline ushort f2bf(float f) {
    uint u = __builtin_bit_cast(uint, f);
    return (ushort)((u + 0x7FFFu + ((u >> 16) & 1u)) >> 16);   // RNE
}
__device__ inline float bf2f(ushort h) {
    uint u = ((uint)h) << 16;
    return __builtin_bit_cast(float, u);
}
__device__ inline float bflo(uint v) { return __builtin_bit_cast(float, v << 16); }
__device__ inline float bfhi(uint v) { return __builtin_bit_cast(float, v & 0xFFFF0000u); }

// ---------------- CSR build ---------------------------------------------------
__global__ __launch_bounds__(256) void hist_kernel(
    const int* __restrict__ ei, int* __restrict__ cnt) {
    int e = blockIdx.x * 256 + threadIdx.x;
    if (e >= NE) return;
    atomicAdd(&cnt[ei[NE + e]], 1);
}

__global__ __launch_bounds__(256) void scan1_kernel(
    const int* __restrict__ cnt, int* __restrict__ off, int* __restrict__ sums) {
    __shared__ int buf[256];
    int t = threadIdx.x;
    int i = blockIdx.x * 256 + t;
    int v = (i < N_NODES) ? cnt[i] : 0;
    buf[t] = v;
    __syncthreads();
#pragma unroll
    for (int d = 1; d < 256; d <<= 1) {
        int add = (t >= d) ? buf[t - d] : 0;
        __syncthreads();
        buf[t] += add;
        __syncthreads();
    }
    if (i < N_NODES) off[i] = buf[t] - v;
    if (t == 255) sums[blockIdx.x] = buf[255];
}

__global__ __launch_bounds__(512) void scan2_kernel(int* __restrict__ sums) {
    __shared__ int buf[512];
    int t = threadIdx.x;
    int v = (t < NBLK_SCAN) ? sums[t] : 0;
    buf[t] = v;
    __syncthreads();
#pragma unroll
    for (int d = 1; d < 512; d <<= 1) {
        int add = (t >= d) ? buf[t - d] : 0;
        __syncthreads();
        buf[t] += add;
        __syncthreads();
    }
    if (t < NBLK_SCAN) sums[t] = buf[t] - v;
}

__global__ __launch_bounds__(256) void scan3_kernel(
    int* __restrict__ off, int* __restrict__ off2, const int* __restrict__ sums) {
    int i = blockIdx.x * 256 + threadIdx.x;
    if (i >= N_NODES) return;
    int o = off[i] + sums[blockIdx.x];
    off[i] = o;
    off2[i] = o;
    if (i == 0) off[N_NODES] = NE;
}

__global__ __launch_bounds__(256) void fill_kernel(
    const int* __restrict__ ei, int* __restrict__ off2, int* __restrict__ srcS) {
    int e = blockIdx.x * 256 + threadIdx.x;
    if (e >= NE) return;
    int src = ei[e];
    int dst = ei[NE + e];
    int pos = atomicAdd(&off2[dst], 1);
    srcS[pos] = src;
}

// -------- prep: x->bf16 (blocks 0..12499), pack W1 (next 128), W2 (next 64) ---
__global__ __launch_bounds__(256) void prep_kernel(
    const float* __restrict__ x, ushort* __restrict__ xb,
    const float* __restrict__ Wl1, const float* __restrict__ Wr1,
    ushort* __restrict__ b1h, ushort* __restrict__ b1l,
    const float* __restrict__ Wl2, const float* __restrict__ Wr2,
    ushort* __restrict__ b2h, ushort* __restrict__ b2l) {
    int b = blockIdx.x;
    if (b < 12500) {
        size_t i = ((size_t)b * 256 + threadIdx.x) * 4;
        float4 v = *reinterpret_cast<const float4*>(x + i);
        ushort4 o;
        o.x = f2bf(v.x); o.y = f2bf(v.y); o.z = f2bf(v.z); o.w = f2bf(v.w);
        *reinterpret_cast<ushort4*>(xb + i) = o;
    } else if (b < 12500 + 128) {
        int gid = (b - 12500) * 256 + threadIdx.x;      // < 32768
        int r = gid & 7, lane = (gid >> 3) & 63, t = (gid >> 9) & 7, ks = gid >> 12;
        int k = ks * 32 + ((lane >> 4) << 3) + r;
        int n = t * 16 + (lane & 15);
        float v = (k < 128) ? Wl1[k * 128 + n] : Wr1[(k - 128) * 128 + n];
        ushort h = f2bf(v);
        b1h[gid] = h;
        b1l[gid] = f2bf(v - bf2f(h));
    } else {
        int gid = (b - 12628) * 256 + threadIdx.x;      // < 16384
        int r = gid & 7, lane = (gid >> 3) & 63, t = (gid >> 9) & 7, ks = gid >> 12;
        int k = ks * 32 + ((lane >> 4) << 3) + r;
        int col = t * 16 + (lane & 15);
        float v = (col < 64) ? Wl2[k * 64 + col] : Wr2[k * 64 + (col - 64)];
        ushort h = f2bf(v);
        b2h[gid] = h;
        b2l[gid] = f2bf(v - bf2f(h));
    }
}

// ------- layer-1 gather mean over bf16 x; writes hi/lo bf16 planes ------------
__global__ __launch_bounds__(256) void agg_mean_kernel(
    const ushort* __restrict__ xb, const int* __restrict__ off,
    const int* __restrict__ srcS, ushort* __restrict__ meanH,
    ushort* __restrict__ meanL) {
    int n = blockIdx.x * 4 + (threadIdx.x >> 6);
    if (n >= N_NODES) return;
    int lane = threadIdx.x & 63;
    int s0 = off[n], s1 = off[n + 1];
    float ax = 0.0f, ay = 0.0f;
    int k = s0;
    for (; k + 4 <= s1; k += 4) {
        int sa = srcS[k], sb = srcS[k + 1], sc = srcS[k + 2], sd = srcS[k + 3];
        uint va = *(const uint*)(xb + (size_t)sa * 128 + lane * 2);
        uint vb = *(const uint*)(xb + (size_t)sb * 128 + lane * 2);
        uint vc = *(const uint*)(xb + (size_t)sc * 128 + lane * 2);
        uint vd = *(const uint*)(xb + (size_t)sd * 128 + lane * 2);
        ax += bflo(va) + bflo(vb) + bflo(vc) + bflo(vd);
        ay += bfhi(va) + bfhi(vb) + bfhi(vc) + bfhi(vd);
    }
    for (; k < s1; ++k) {
        uint v = *(const uint*)(xb + (size_t)srcS[k] * 128 + lane * 2);
        ax += bflo(v);
        ay += bfhi(v);
    }
    float inv = (s1 > s0) ? 1.0f / (float)(s1 - s0) : 0.0f;
    float mx = ax * inv, my = ay * inv;
    ushort hx = f2bf(mx), hy = f2bf(my);
    ushort lx = f2bf(mx - bf2f(hx)), ly = f2bf(my - bf2f(hy));
    *(uint*)(meanH + (size_t)n * 128 + lane * 2) = (uint)hx | ((uint)hy << 16);
    *(uint*)(meanL + (size_t)n * 128 + lane * 2) = (uint)lx | ((uint)ly << 16);
}

// ------- GEMM 1: h = relu([mean|x] @ [Wl1;Wr1] + b1) --------------------------
// 256 blocks x 768 threads; B staged in LDS (128KB); each wave: pair of 16-row
// tiles sharing each B-fragment read.
__global__ __launch_bounds__(768) void gemm1_kernel(
    const ushort* __restrict__ meanH, const ushort* __restrict__ meanL,
    const ushort* __restrict__ xb,
    const ushort* __restrict__ bh, const ushort* __restrict__ bl,
    const float* __restrict__ b1, ushort* __restrict__ hb) {
    __shared__ __align__(16) ushort Bs0[32768];
    __shared__ __align__(16) ushort Bs1[32768];
    int tid = threadIdx.x;
    for (int j = tid; j < 4096; j += 768) {
        ((ushort8v*)Bs0)[j] = ((const ushort8v*)bh)[j];
        ((ushort8v*)Bs1)[j] = ((const ushort8v*)bl)[j];
    }
    __syncthreads();
    int w = tid >> 6, lane = tid & 63;
    int lrow = lane & 15, kg = lane >> 4;
    const f32x4 z4 = {0.f, 0.f, 0.f, 0.f};
    for (int idx = blockIdx.x * 12 + w; idx < 3125; idx += 3072) {
        size_t r0 = (size_t)idx * 32;   // two tiles: rows [r0,r0+16), [r0+16,r0+32)
        f32x4 acc[2][8];
#pragma unroll
        for (int s = 0; s < 2; ++s)
#pragma unroll
            for (int t = 0; t < 8; ++t) acc[s][t] = z4;
#pragma unroll
        for (int ks = 0; ks < 8; ++ks) {
            bf16x8 aH0, aL0, aH1, aL1;
            if (ks < 4) {
                aH0 = *(const bf16x8*)(meanH + (r0 + lrow) * 128 + ks * 32 + kg * 8);
                aL0 = *(const bf16x8*)(meanL + (r0 + lrow) * 128 + ks * 32 + kg * 8);
                aH1 = *(const bf16x8*)(meanH + (r0 + 16 + lrow) * 128 + ks * 32 + kg * 8);
                aL1 = *(const bf16x8*)(meanL + (r0 + 16 + lrow) * 128 + ks * 32 + kg * 8);
            } else {
                aH0 = *(const bf16x8*)(xb + (r0 + lrow) * 128 + (ks - 4) * 32 + kg * 8);
                aH1 = *(const bf16x8*)(xb + (r0 + 16 + lrow) * 128 + (ks - 4) * 32 + kg * 8);
            }
#pragma unroll
            for (int t = 0; t < 8; ++t) {
                bf16x8 Bh = *(const bf16x8*)&Bs0[(size_t)((ks * 8 + t) * 64 + lane) * 8];
                bf16x8 Bl = *(const bf16x8*)&Bs1[(size_t)((ks * 8 + t) * 64 + lane) * 8];
                acc[0][t] = __builtin_amdgcn_mfma_f32_16x16x32_bf16(aH0, Bh, acc[0][t], 0, 0, 0);
                acc[0][t] = __builtin_amdgcn_mfma_f32_16x16x32_bf16(aH0, Bl, acc[0][t], 0, 0, 0);
                acc[1][t] = __builtin_amdgcn_mfma_f32_16x16x32_bf16(aH1, Bh, acc[1][t], 0, 0, 0);
                acc[1][t] = __builtin_amdgcn_mfma_f32_16x16x32_bf16(aH1, Bl, acc[1][t], 0, 0, 0);
                if (ks < 4) {
                    acc[0][t] = __builtin_amdgcn_mfma_f32_16x16x32_bf16(aL0, Bh, acc[0][t], 0, 0, 0);
                    acc[1][t] = __builtin_amdgcn_mfma_f32_16x16x32_bf16(aL1, Bh, acc[1][t], 0, 0, 0);
                }
            }
        }
#pragma unroll
        for (int t = 0; t < 8; ++t) {
            float bj = b1[t * 16 + lrow];
#pragma unroll
            for (int s = 0; s < 2; ++s)
#pragma unroll
                for (int rg = 0; rg < 4; ++rg) {
                    size_t row = r0 + s * 16 + kg * 4 + rg;
                    hb[row * 128 + t * 16 + lrow] = f2bf(fmaxf(acc[s][t][rg] + bj, 0.0f));
                }
        }
    }
}

// ------- GEMM 2: [t|u] = h @ [Wl2|Wr2] ----------------------------------------
__global__ __launch_bounds__(768) void gemm2_kernel(
    const ushort* __restrict__ hb,
    const ushort* __restrict__ bh, const ushort* __restrict__ bl,
    ushort* __restrict__ tb, ushort* __restrict__ ub) {
    __shared__ __align__(16) ushort Bs0[16384];
    __shared__ __align__(16) ushort Bs1[16384];
    int tid = threadIdx.x;
    for (int j = tid; j < 2048; j += 768) {
        ((ushort8v*)Bs0)[j] = ((const ushort8v*)bh)[j];
        ((ushort8v*)Bs1)[j] = ((const ushort8v*)bl)[j];
    }
    __syncthreads();
    int w = tid >> 6, lane = tid & 63;
    int lrow = lane & 15, kg = lane >> 4;
    const f32x4 z4 = {0.f, 0.f, 0.f, 0.f};
    for (int idx = blockIdx.x * 12 + w; idx < 3125; idx += 3072) {
        size_t r0 = (size_t)idx * 32;
        f32x4 acc[2][8];
#pragma unroll
        for (int s = 0; s < 2; ++s)
#pragma unroll
            for (int t = 0; t < 8; ++t) acc[s][t] = z4;
#pragma unroll
        for (int ks = 0; ks < 4; ++ks) {
            bf16x8 aH0 = *(const bf16x8*)(hb + (r0 + lrow) * 128 + ks * 32 + kg * 8);
            bf16x8 aH1 = *(const bf16x8*)(hb + (r0 + 16 + lrow) * 128 + ks * 32 + kg * 8);
#pragma unroll
            for (int t = 0; t < 8; ++t) {
                bf16x8 Bh = *(const bf16x8*)&Bs0[(size_t)((ks * 8 + t) * 64 + lane) * 8];
                bf16x8 Bl = *(const bf16x8*)&Bs1[(size_t)((ks * 8 + t) * 64 + lane) * 8];
                acc[0][t] = __builtin_amdgcn_mfma_f32_16x16x32_bf16(aH0, Bh, acc[0][t], 0, 0, 0);
                acc[0][t] = __builtin_amdgcn_mfma_f32_16x16x32_bf16(aH0, Bl, acc[0][t], 0, 0, 0);
                acc[1][t] = __builtin_amdgcn_mfma_f32_16x16x32_bf16(aH1, Bh, acc[1][t], 0, 0, 0);
                acc[1][t] = __builtin_amdgcn_mfma_f32_16x16x32_bf16(aH1, Bl, acc[1][t], 0, 0, 0);
            }
        }
#pragma unroll
        for (int t = 0; t < 8; ++t) {
#pragma unroll
            for (int s = 0; s < 2; ++s)
#pragma unroll
                for (int rg = 0; rg < 4; ++rg) {
                    size_t row = r0 + s * 16 + kg * 4 + rg;
                    int col = t * 16 + lrow;
                    if (t < 4) tb[row * 64 + col] = f2bf(acc[s][t][rg]);
                    else       ub[row * 64 + (col - 64)] = f2bf(acc[s][t][rg]);
                }
        }
    }
}

// ------- layer-2 gather (bf16 t, chunk-4) + combine: z = mean(t)+u+b2 ---------
__global__ __launch_bounds__(256) void agg_z_kernel(
    const ushort* __restrict__ tb, const ushort* __restrict__ ub,
    const float* __restrict__ b2, const int* __restrict__ off,
    const int* __restrict__ srcS, ushort* __restrict__ zb) {
    int n = blockIdx.x * 8 + (threadIdx.x >> 5);   // 2 nodes per wave
    if (n >= N_NODES) return;
    int l = threadIdx.x & 31;                      // channels 2l, 2l+1
    int s0 = off[n], s1 = off[n + 1];
    float ax = 0.0f, ay = 0.0f;
    int k = s0;
    for (; k + 4 <= s1; k += 4) {
        int sa = srcS[k], sb = srcS[k + 1], sc = srcS[k + 2], sd = srcS[k + 3];
        uint va = *(const uint*)(tb + (size_t)sa * 64 + l * 2);
        uint vb = *(const uint*)(tb + (size_t)sb * 64 + l * 2);
        uint vc = *(const uint*)(tb + (size_t)sc * 64 + l * 2);
        uint vd = *(const uint*)(tb + (size_t)sd * 64 + l * 2);
        ax += bflo(va) + bflo(vb) + bflo(vc) + bflo(vd);
        ay += bfhi(va) + bfhi(vb) + bfhi(vc) + bfhi(vd);
    }
    for (; k < s1; ++k) {
        uint v = *(const uint*)(tb + (size_t)srcS[k] * 64 + l * 2);
        ax += bflo(v);
        ay += bfhi(v);
    }
    float inv = (s1 > s0) ? 1.0f / (float)(s1 - s0) : 0.0f;
    uint uu = *(const uint*)(ub + (size_t)n * 64 + l * 2);
    float zx = ax * inv + bflo(uu) + b2[l * 2];
    float zy = ay * inv + bfhi(uu) + b2[l * 2 + 1];
    uint pz = (uint)f2bf(zx) | ((uint)f2bf(zy) << 16);
    *(uint*)(zb + (size_t)n * 64 + l * 2) = pz;
}

// ---------------- decode over bf16 z ------------------------------------------
__global__ __launch_bounds__(256) void decode_kernel(
    const ushort* __restrict__ zb,
    const int* __restrict__ pos, const int* __restrict__ neg,
    float* __restrict__ out) {
    int t = blockIdx.x * 256 + threadIdx.x;
    int g = t >> 4;
    int lane = t & 15;
    if (g >= 2 * NEP) return;
    const int* ei;
    int e;
    float* o;
    if (g < NEP) { ei = pos; e = g; o = out; }
    else         { ei = neg; e = g - NEP; o = out + NEP; }
    int a  = ei[e];
    int bn = ei[NEP + e];
    ushort4 va = *reinterpret_cast<const ushort4*>(zb + (size_t)a  * 64 + lane * 4);
    ushort4 vb = *reinterpret_cast<const ushort4*>(zb + (size_t)bn * 64 + lane * 4);
    float s = bf2f(va.x) * bf2f(vb.x) + bf2f(va.y) * bf2f(vb.y)
            + bf2f(va.z) * bf2f(vb.z) + bf2f(va.w) * bf2f(vb.w);
    s += __shfl_xor(s, 1);
    s += __shfl_xor(s, 2);
    s += __shfl_xor(s, 4);
    s += __shfl_xor(s, 8);
    if (lane == 0) o[e] = s;
}

extern "C" void kernel_launch(void* const* d_in, const int* in_sizes, int n_in,
                              void* d_out, int out_size, void* d_ws, size_t ws_size,
                              hipStream_t stream) {
    const float* x    = (const float*)d_in[0];
    const int*   ei   = (const int*)d_in[1];
    const int*   pos  = (const int*)d_in[2];
    const int*   neg  = (const int*)d_in[3];
    const float* Wl1  = (const float*)d_in[4];
    const float* Wr1  = (const float*)d_in[5];
    const float* b1   = (const float*)d_in[6];
    const float* Wl2  = (const float*)d_in[7];
    const float* Wr2  = (const float*)d_in[8];
    const float* b2   = (const float*)d_in[9];
    float* out = (float*)d_out;

    const size_t HALF = (size_t)N_NODES * 128 * 2;   // 25.6 MB (one bf16 plane)
    char* ws = (char*)d_ws;
    // region1: xb plane | hb plane (both live during gemm1)
    ushort* xb = (ushort*)ws;                        // N*128 bf16
    ushort* hb = (ushort*)(ws + HALF);               // N*128 bf16
    // region2: meanH | meanL planes; after gemm1 reused by tb|ub|zb
    ushort* meanH = (ushort*)(ws + 2 * HALF);        // N*128 bf16
    ushort* meanL = (ushort*)(ws + 3 * HALF);        // N*128 bf16
    ushort* tb = (ushort*)(ws + 2 * HALF);                               // N*64 bf16
    ushort* ub = (ushort*)(ws + 2 * HALF + (size_t)N_NODES * 64 * 2);    // N*64 bf16
    ushort* zb = (ushort*)(ws + 2 * HALF + (size_t)N_NODES * 64 * 4);    // N*64 bf16
    // ints + packed weights
    int* cnt  = (int*)(ws + 4 * HALF);
    int* off  = cnt + N_NODES;
    int* off2 = off + N_NODES + 1;
    int* srcS = off2 + N_NODES;
    int* sums = srcS + NE;
    ushort* b1h = (ushort*)(sums + 512);
    ushort* b1l = b1h + 32768;
    ushort* b2h = b1l + 32768;
    ushort* b2l = b2h + 16384;

    // ---- CSR build ----
    hipMemsetAsync(cnt, 0, N_NODES * sizeof(int), stream);
    hist_kernel <<<(NE + 255) / 256, 256, 0, stream>>>(ei, cnt);
    scan1_kernel<<<NBLK_SCAN, 256, 0, stream>>>(cnt, off, sums);
    scan2_kernel<<<1, 512, 0, stream>>>(sums);
    scan3_kernel<<<NBLK_SCAN, 256, 0, stream>>>(off, off2, sums);
    fill_kernel <<<(NE + 255) / 256, 256, 0, stream>>>(ei, off2, srcS);

    // ---- prep: x->bf16 + weight packing (one kernel) ----
    prep_kernel<<<12692, 256, 0, stream>>>(x, xb, Wl1, Wr1, b1h, b1l,
                                           Wl2, Wr2, b2h, b2l);

    // ---- layer 1 ----
    agg_mean_kernel<<<N_NODES / 4, 256, 0, stream>>>(xb, off, srcS, meanH, meanL);
    gemm1_kernel<<<256, 768, 0, stream>>>(meanH, meanL, xb, b1h, b1l, b1, hb);

    // ---- layer 2 (transform-then-aggregate) ----
    gemm2_kernel<<<256, 768, 0, stream>>>(hb, b2h, b2l, tb, ub);
    agg_z_kernel<<<(N_NODES + 7) / 8, 256, 0, stream>>>(tb, ub, b2, off, srcS, zb);

    // ---- decode ----
    decode_kernel<<<(2 * NEP * 16) / 256, 256, 0, stream>>>(zb, pos, neg, out);
}

// Round 7
// 210.257 us; speedup vs baseline: 2.5449x; 2.5449x over previous
//
#include <hip/hip_runtime.h>

#define N_NODES 100000
#define NE 500000
#define NEP 100000
#define NBLK_SCAN ((N_NODES + 255) / 256)   // 391

typedef short bf16x8 __attribute__((ext_vector_type(8)));
typedef float f32x4  __attribute__((ext_vector_type(4)));

__device__ inline ushort f2bf(float f) {
    uint u = __builtin_bit_cast(uint, f);
    return (ushort)((u + 0x7FFFu + ((u >> 16) & 1u)) >> 16);   // RNE
}
__device__ inline float bf2f(ushort h) {
    uint u = ((uint)h) << 16;
    return __builtin_bit_cast(float, u);
}
__device__ inline float bflo(uint v) { return __builtin_bit_cast(float, v << 16); }
__device__ inline float bfhi(uint v) { return __builtin_bit_cast(float, v & 0xFFFF0000u); }

// ---------------- CSR build ---------------------------------------------------
__global__ __launch_bounds__(256) void hist_kernel(
    const int* __restrict__ ei, int* __restrict__ cnt) {
    int e = blockIdx.x * 256 + threadIdx.x;
    if (e >= NE) return;
    atomicAdd(&cnt[ei[NE + e]], 1);
}

__global__ __launch_bounds__(256) void scan1_kernel(
    const int* __restrict__ cnt, int* __restrict__ off, int* __restrict__ sums) {
    __shared__ int buf[256];
    int t = threadIdx.x;
    int i = blockIdx.x * 256 + t;
    int v = (i < N_NODES) ? cnt[i] : 0;
    buf[t] = v;
    __syncthreads();
#pragma unroll
    for (int d = 1; d < 256; d <<= 1) {
        int add = (t >= d) ? buf[t - d] : 0;
        __syncthreads();
        buf[t] += add;
        __syncthreads();
    }
    if (i < N_NODES) off[i] = buf[t] - v;
    if (t == 255) sums[blockIdx.x] = buf[255];
}

__global__ __launch_bounds__(512) void scan2_kernel(int* __restrict__ sums) {
    __shared__ int buf[512];
    int t = threadIdx.x;
    int v = (t < NBLK_SCAN) ? sums[t] : 0;
    buf[t] = v;
    __syncthreads();
#pragma unroll
    for (int d = 1; d < 512; d <<= 1) {
        int add = (t >= d) ? buf[t - d] : 0;
        __syncthreads();
        buf[t] += add;
        __syncthreads();
    }
    if (t < NBLK_SCAN) sums[t] = buf[t] - v;
}

__global__ __launch_bounds__(256) void scan3_kernel(
    int* __restrict__ off, int* __restrict__ off2, const int* __restrict__ sums) {
    int i = blockIdx.x * 256 + threadIdx.x;
    if (i >= N_NODES) return;
    int o = off[i] + sums[blockIdx.x];
    off[i] = o;
    off2[i] = o;
    if (i == 0) off[N_NODES] = NE;
}

__global__ __launch_bounds__(256) void fill_kernel(
    const int* __restrict__ ei, int* __restrict__ off2, int* __restrict__ srcS) {
    int e = blockIdx.x * 256 + threadIdx.x;
    if (e >= NE) return;
    int src = ei[e];
    int dst = ei[NE + e];
    int pos = atomicAdd(&off2[dst], 1);
    srcS[pos] = src;
}

// -------- prep: x->bf16 (blocks 0..12499), pack W1 (next 128), W2 (next 64) ---
__global__ __launch_bounds__(256) void prep_kernel(
    const float* __restrict__ x, ushort* __restrict__ xb,
    const float* __restrict__ Wl1, const float* __restrict__ Wr1,
    ushort* __restrict__ b1h, ushort* __restrict__ b1l,
    const float* __restrict__ Wl2, const float* __restrict__ Wr2,
    ushort* __restrict__ b2h, ushort* __restrict__ b2l) {
    int b = blockIdx.x;
    if (b < 12500) {
        size_t i = ((size_t)b * 256 + threadIdx.x) * 4;
        float4 v = *reinterpret_cast<const float4*>(x + i);
        ushort4 o;
        o.x = f2bf(v.x); o.y = f2bf(v.y); o.z = f2bf(v.z); o.w = f2bf(v.w);
        *reinterpret_cast<ushort4*>(xb + i) = o;
    } else if (b < 12500 + 128) {
        int gid = (b - 12500) * 256 + threadIdx.x;      // < 32768
        int r = gid & 7, lane = (gid >> 3) & 63, t = (gid >> 9) & 7, ks = gid >> 12;
        int k = ks * 32 + ((lane >> 4) << 3) + r;
        int n = t * 16 + (lane & 15);
        float v = (k < 128) ? Wl1[k * 128 + n] : Wr1[(k - 128) * 128 + n];
        ushort h = f2bf(v);
        b1h[gid] = h;
        b1l[gid] = f2bf(v - bf2f(h));
    } else {
        int gid = (b - 12628) * 256 + threadIdx.x;      // < 16384
        int r = gid & 7, lane = (gid >> 3) & 63, t = (gid >> 9) & 7, ks = gid >> 12;
        int k = ks * 32 + ((lane >> 4) << 3) + r;
        int col = t * 16 + (lane & 15);
        float v = (col < 64) ? Wl2[k * 64 + col] : Wr2[k * 64 + (col - 64)];
        ushort h = f2bf(v);
        b2h[gid] = h;
        b2l[gid] = f2bf(v - bf2f(h));
    }
}

// ------- layer-1 gather mean over bf16 x; writes hi/lo bf16 planes ------------
__global__ __launch_bounds__(256) void agg_mean_kernel(
    const ushort* __restrict__ xb, const int* __restrict__ off,
    const int* __restrict__ srcS, ushort* __restrict__ meanH,
    ushort* __restrict__ meanL) {
    int n = blockIdx.x * 4 + (threadIdx.x >> 6);
    if (n >= N_NODES) return;
    int lane = threadIdx.x & 63;
    int s0 = off[n], s1 = off[n + 1];
    float ax = 0.0f, ay = 0.0f;
    int k = s0;
    for (; k + 4 <= s1; k += 4) {
        int sa = srcS[k], sb = srcS[k + 1], sc = srcS[k + 2], sd = srcS[k + 3];
        uint va = *(const uint*)(xb + (size_t)sa * 128 + lane * 2);
        uint vb = *(const uint*)(xb + (size_t)sb * 128 + lane * 2);
        uint vc = *(const uint*)(xb + (size_t)sc * 128 + lane * 2);
        uint vd = *(const uint*)(xb + (size_t)sd * 128 + lane * 2);
        ax += bflo(va) + bflo(vb) + bflo(vc) + bflo(vd);
        ay += bfhi(va) + bfhi(vb) + bfhi(vc) + bfhi(vd);
    }
    for (; k < s1; ++k) {
        uint v = *(const uint*)(xb + (size_t)srcS[k] * 128 + lane * 2);
        ax += bflo(v);
        ay += bfhi(v);
    }
    float inv = (s1 > s0) ? 1.0f / (float)(s1 - s0) : 0.0f;
    float mx = ax * inv, my = ay * inv;
    ushort hx = f2bf(mx), hy = f2bf(my);
    ushort lx = f2bf(mx - bf2f(hx)), ly = f2bf(my - bf2f(hy));
    *(uint*)(meanH + (size_t)n * 128 + lane * 2) = (uint)hx | ((uint)hy << 16);
    *(uint*)(meanL + (size_t)n * 128 + lane * 2) = (uint)lx | ((uint)ly << 16);
}

// ------- fused MLP: h = relu([mean|x]@W1 + b1) ; [t|u] = h@W2 -----------------
// 16 rows/wave, 4 waves/block. h tile bounced through wave-private swizzled LDS.
__global__ __launch_bounds__(256) void mlp_kernel(
    const ushort* __restrict__ meanH, const ushort* __restrict__ meanL,
    const ushort* __restrict__ xb,
    const ushort* __restrict__ b1hp_, const ushort* __restrict__ b1lp_,
    const float* __restrict__ b1,
    const ushort* __restrict__ b2hp_, const ushort* __restrict__ b2lp_,
    ushort* __restrict__ tb, ushort* __restrict__ ub) {
    __shared__ __align__(16) ushort hs[4][2048];   // 4 waves x 4KB
    int wid = blockIdx.x * 4 + (threadIdx.x >> 6);
    if (wid >= N_NODES / 16) return;
    int lane = threadIdx.x & 63;
    int lrow = lane & 15, kg = lane >> 4;
    size_t r0 = (size_t)wid * 16;
    char* hw = (char*)&hs[threadIdx.x >> 6][0];
    const bf16x8* b1hp = (const bf16x8*)b1hp_;
    const bf16x8* b1lp = (const bf16x8*)b1lp_;
    const bf16x8* b2hp = (const bf16x8*)b2hp_;
    const bf16x8* b2lp = (const bf16x8*)b2lp_;
    const f32x4 z4 = {0.f, 0.f, 0.f, 0.f};

    // ---- phase A: layer-1 GEMM ----
    f32x4 acc[8];
#pragma unroll
    for (int t = 0; t < 8; ++t) acc[t] = z4;
#pragma unroll
    for (int ks = 0; ks < 8; ++ks) {
        bf16x8 aH, aL;
        if (ks < 4) {
            aH = *(const bf16x8*)(meanH + (r0 + lrow) * 128 + ks * 32 + kg * 8);
            aL = *(const bf16x8*)(meanL + (r0 + lrow) * 128 + ks * 32 + kg * 8);
        } else {
            aH = *(const bf16x8*)(xb + (r0 + lrow) * 128 + (ks - 4) * 32 + kg * 8);
        }
#pragma unroll
        for (int t = 0; t < 8; ++t) {
            bf16x8 Bh = b1hp[(ks * 8 + t) * 64 + lane];
            bf16x8 Bl = b1lp[(ks * 8 + t) * 64 + lane];
            acc[t] = __builtin_amdgcn_mfma_f32_16x16x32_bf16(aH, Bh, acc[t], 0, 0, 0);
            acc[t] = __builtin_amdgcn_mfma_f32_16x16x32_bf16(aH, Bl, acc[t], 0, 0, 0);
            if (ks < 4)
                acc[t] = __builtin_amdgcn_mfma_f32_16x16x32_bf16(aL, Bh, acc[t], 0, 0, 0);
        }
    }
    // ---- epilogue A: bias + relu -> swizzled LDS h tile (16x128 bf16) ----
#pragma unroll
    for (int t = 0; t < 8; ++t) {
        float bj = b1[t * 16 + lrow];
#pragma unroll
        for (int rg = 0; rg < 4; ++rg) {
            int row = kg * 4 + rg;
            int col2 = (t * 16 + lrow) * 2;
            int byte = row * 256 + (col2 ^ ((row & 7) << 4));
            *(ushort*)(hw + byte) = f2bf(fmaxf(acc[t][rg] + bj, 0.0f));
        }
    }
    // (wave-private tile: no barrier; compiler orders via lgkmcnt)

    // ---- phase B: layer-2 GEMM from LDS h ----
    f32x4 acc2[8];
#pragma unroll
    for (int t = 0; t < 8; ++t) acc2[t] = z4;
#pragma unroll
    for (int ks = 0; ks < 4; ++ks) {
        int byte = lrow * 256 + ((ks * 64 + kg * 16) ^ ((lrow & 7) << 4));
        bf16x8 aH = *(const bf16x8*)(hw + byte);
#pragma unroll
        for (int t = 0; t < 8; ++t) {
            bf16x8 Bh = b2hp[(ks * 8 + t) * 64 + lane];
            bf16x8 Bl = b2lp[(ks * 8 + t) * 64 + lane];
            acc2[t] = __builtin_amdgcn_mfma_f32_16x16x32_bf16(aH, Bh, acc2[t], 0, 0, 0);
            acc2[t] = __builtin_amdgcn_mfma_f32_16x16x32_bf16(aH, Bl, acc2[t], 0, 0, 0);
        }
    }
    // ---- epilogue B: write t|u ----
#pragma unroll
    for (int t = 0; t < 8; ++t) {
#pragma unroll
        for (int rg = 0; rg < 4; ++rg) {
            size_t row = r0 + kg * 4 + rg;
            int col = t * 16 + lrow;
            if (t < 4) tb[row * 64 + col] = f2bf(acc2[t][rg]);
            else       ub[row * 64 + (col - 64)] = f2bf(acc2[t][rg]);
        }
    }
}

// ------- layer-2 gather (bf16 t, chunk-4) + combine: z = mean(t)+u+b2 ---------
__global__ __launch_bounds__(256) void agg_z_kernel(
    const ushort* __restrict__ tb, const ushort* __restrict__ ub,
    const float* __restrict__ b2, const int* __restrict__ off,
    const int* __restrict__ srcS, ushort* __restrict__ zb) {
    int n = blockIdx.x * 8 + (threadIdx.x >> 5);   // 2 nodes per wave
    if (n >= N_NODES) return;
    int l = threadIdx.x & 31;                      // channels 2l, 2l+1
    int s0 = off[n], s1 = off[n + 1];
    float ax = 0.0f, ay = 0.0f;
    int k = s0;
    for (; k + 4 <= s1; k += 4) {
        int sa = srcS[k], sb = srcS[k + 1], sc = srcS[k + 2], sd = srcS[k + 3];
        uint va = *(const uint*)(tb + (size_t)sa * 64 + l * 2);
        uint vb = *(const uint*)(tb + (size_t)sb * 64 + l * 2);
        uint vc = *(const uint*)(tb + (size_t)sc * 64 + l * 2);
        uint vd = *(const uint*)(tb + (size_t)sd * 64 + l * 2);
        ax += bflo(va) + bflo(vb) + bflo(vc) + bflo(vd);
        ay += bfhi(va) + bfhi(vb) + bfhi(vc) + bfhi(vd);
    }
    for (; k < s1; ++k) {
        uint v = *(const uint*)(tb + (size_t)srcS[k] * 64 + l * 2);
        ax += bflo(v);
        ay += bfhi(v);
    }
    float inv = (s1 > s0) ? 1.0f / (float)(s1 - s0) : 0.0f;
    uint uu = *(const uint*)(ub + (size_t)n * 64 + l * 2);
    float zx = ax * inv + bflo(uu) + b2[l * 2];
    float zy = ay * inv + bfhi(uu) + b2[l * 2 + 1];
    uint pz = (uint)f2bf(zx) | ((uint)f2bf(zy) << 16);
    *(uint*)(zb + (size_t)n * 64 + l * 2) = pz;
}

// ---------------- decode over bf16 z ------------------------------------------
__global__ __launch_bounds__(256) void decode_kernel(
    const ushort* __restrict__ zb,
    const int* __restrict__ pos, const int* __restrict__ neg,
    float* __restrict__ out) {
    int t = blockIdx.x * 256 + threadIdx.x;
    int g = t >> 4;
    int lane = t & 15;
    if (g >= 2 * NEP) return;
    const int* ei;
    int e;
    float* o;
    if (g < NEP) { ei = pos; e = g; o = out; }
    else         { ei = neg; e = g - NEP; o = out + NEP; }
    int a  = ei[e];
    int bn = ei[NEP + e];
    ushort4 va = *reinterpret_cast<const ushort4*>(zb + (size_t)a  * 64 + lane * 4);
    ushort4 vb = *reinterpret_cast<const ushort4*>(zb + (size_t)bn * 64 + lane * 4);
    float s = bf2f(va.x) * bf2f(vb.x) + bf2f(va.y) * bf2f(vb.y)
            + bf2f(va.z) * bf2f(vb.z) + bf2f(va.w) * bf2f(vb.w);
    s += __shfl_xor(s, 1);
    s += __shfl_xor(s, 2);
    s += __shfl_xor(s, 4);
    s += __shfl_xor(s, 8);
    if (lane == 0) o[e] = s;
}

extern "C" void kernel_launch(void* const* d_in, const int* in_sizes, int n_in,
                              void* d_out, int out_size, void* d_ws, size_t ws_size,
                              hipStream_t stream) {
    const float* x    = (const float*)d_in[0];
    const int*   ei   = (const int*)d_in[1];
    const int*   pos  = (const int*)d_in[2];
    const int*   neg  = (const int*)d_in[3];
    const float* Wl1  = (const float*)d_in[4];
    const float* Wr1  = (const float*)d_in[5];
    const float* b1   = (const float*)d_in[6];
    const float* Wl2  = (const float*)d_in[7];
    const float* Wr2  = (const float*)d_in[8];
    const float* b2   = (const float*)d_in[9];
    float* out = (float*)d_out;

    const size_t HALF = (size_t)N_NODES * 128 * 2;   // 25.6 MB (one bf16 plane)
    const size_t QTR  = (size_t)N_NODES * 64 * 2;    // 12.8 MB
    char* ws = (char*)d_ws;
    ushort* xb    = (ushort*)ws;                     // N*128 bf16
    ushort* meanH = (ushort*)(ws + HALF);            // N*128 bf16
    ushort* meanL = (ushort*)(ws + 2 * HALF);        // N*128 bf16
    ushort* tb    = (ushort*)(ws + 3 * HALF);                 // N*64 bf16
    ushort* ub    = (ushort*)(ws + 3 * HALF + QTR);           // N*64 bf16
    ushort* zb    = (ushort*)(ws + 3 * HALF + 2 * QTR);       // N*64 bf16
    // ints + packed weights
    int* cnt  = (int*)(ws + 3 * HALF + 3 * QTR);
    int* off  = cnt + N_NODES;
    int* off2 = off + N_NODES + 1;
    int* srcS = off2 + N_NODES;
    int* sums = srcS + NE;
    ushort* b1h = (ushort*)(sums + 512);
    ushort* b1l = b1h + 32768;
    ushort* b2h = b1l + 32768;
    ushort* b2l = b2h + 16384;

    // ---- CSR build ----
    hipMemsetAsync(cnt, 0, N_NODES * sizeof(int), stream);
    hist_kernel <<<(NE + 255) / 256, 256, 0, stream>>>(ei, cnt);
    scan1_kernel<<<NBLK_SCAN, 256, 0, stream>>>(cnt, off, sums);
    scan2_kernel<<<1, 512, 0, stream>>>(sums);
    scan3_kernel<<<NBLK_SCAN, 256, 0, stream>>>(off, off2, sums);
    fill_kernel <<<(NE + 255) / 256, 256, 0, stream>>>(ei, off2, srcS);

    // ---- prep: x->bf16 + weight packing (one kernel) ----
    prep_kernel<<<12692, 256, 0, stream>>>(x, xb, Wl1, Wr1, b1h, b1l,
                                           Wl2, Wr2, b2h, b2l);

    // ---- layer 1 aggregate ----
    agg_mean_kernel<<<N_NODES / 4, 256, 0, stream>>>(xb, off, srcS, meanH, meanL);

    // ---- fused MLP (layer-1 GEMM + relu + layer-2 GEMM) ----
    mlp_kernel<<<(N_NODES / 16 + 3) / 4, 256, 0, stream>>>(
        meanH, meanL, xb, b1h, b1l, b1, b2h, b2l, tb, ub);

    // ---- layer 2 aggregate + combine ----
    agg_z_kernel<<<(N_NODES + 7) / 8, 256, 0, stream>>>(tb, ub, b2, off, srcS, zb);

    // ---- decode ----
    decode_kernel<<<(2 * NEP * 16) / 256, 256, 0, stream>>>(zb, pos, neg, out);
}

// Round 8
// 202.868 us; speedup vs baseline: 2.6376x; 1.0364x over previous
//
#include <hip/hip_runtime.h>

#define N_NODES 100000
#define NE 500000
#define NEP 100000
#define NBLK_SCAN ((N_NODES + 255) / 256)   // 391

typedef short bf16x8 __attribute__((ext_vector_type(8)));
typedef float f32x4  __attribute__((ext_vector_type(4)));
typedef ushort ushort8v __attribute__((ext_vector_type(8)));

__device__ inline ushort f2bf(float f) {
    uint u = __builtin_bit_cast(uint, f);
    return (ushort)((u + 0x7FFFu + ((u >> 16) & 1u)) >> 16);   // RNE
}
__device__ inline float bf2f(ushort h) {
    uint u = ((uint)h) << 16;
    return __builtin_bit_cast(float, u);
}
__device__ inline float bflo(uint v) { return __builtin_bit_cast(float, v << 16); }
__device__ inline float bfhi(uint v) { return __builtin_bit_cast(float, v & 0xFFFF0000u); }

// ---------------- CSR build ---------------------------------------------------
__global__ __launch_bounds__(256) void hist_kernel(
    const int* __restrict__ ei, int* __restrict__ cnt) {
    int e = blockIdx.x * 256 + threadIdx.x;
    if (e >= NE) return;
    atomicAdd(&cnt[ei[NE + e]], 1);
}

__global__ __launch_bounds__(256) void scan1_kernel(
    const int* __restrict__ cnt, int* __restrict__ off, int* __restrict__ sums) {
    __shared__ int buf[256];
    int t = threadIdx.x;
    int i = blockIdx.x * 256 + t;
    int v = (i < N_NODES) ? cnt[i] : 0;
    buf[t] = v;
    __syncthreads();
#pragma unroll
    for (int d = 1; d < 256; d <<= 1) {
        int add = (t >= d) ? buf[t - d] : 0;
        __syncthreads();
        buf[t] += add;
        __syncthreads();
    }
    if (i < N_NODES) off[i] = buf[t] - v;
    if (t == 255) sums[blockIdx.x] = buf[255];
}

__global__ __launch_bounds__(512) void scan2_kernel(int* __restrict__ sums) {
    __shared__ int buf[512];
    int t = threadIdx.x;
    int v = (t < NBLK_SCAN) ? sums[t] : 0;
    buf[t] = v;
    __syncthreads();
#pragma unroll
    for (int d = 1; d < 512; d <<= 1) {
        int add = (t >= d) ? buf[t - d] : 0;
        __syncthreads();
        buf[t] += add;
        __syncthreads();
    }
    if (t < NBLK_SCAN) sums[t] = buf[t] - v;
}

__global__ __launch_bounds__(256) void scan3_kernel(
    int* __restrict__ off, int* __restrict__ off2, const int* __restrict__ sums) {
    int i = blockIdx.x * 256 + threadIdx.x;
    if (i >= N_NODES) return;
    int o = off[i] + sums[blockIdx.x];
    off[i] = o;
    off2[i] = o;
    if (i == 0) off[N_NODES] = NE;
}

__global__ __launch_bounds__(256) void fill_kernel(
    const int* __restrict__ ei, int* __restrict__ off2, int* __restrict__ srcS) {
    int e = blockIdx.x * 256 + threadIdx.x;
    if (e >= NE) return;
    int src = ei[e];
    int dst = ei[NE + e];
    int pos = atomicAdd(&off2[dst], 1);
    srcS[pos] = src;
}

// -------- prep: x->bf16 (blocks 0..12499), pack W1 (next 128), W2 (next 64) ---
__global__ __launch_bounds__(256) void prep_kernel(
    const float* __restrict__ x, ushort* __restrict__ xb,
    const float* __restrict__ Wl1, const float* __restrict__ Wr1,
    ushort* __restrict__ b1h, ushort* __restrict__ b1l,
    const float* __restrict__ Wl2, const float* __restrict__ Wr2,
    ushort* __restrict__ b2h, ushort* __restrict__ b2l) {
    int b = blockIdx.x;
    if (b < 12500) {
        size_t i = ((size_t)b * 256 + threadIdx.x) * 4;
        float4 v = *reinterpret_cast<const float4*>(x + i);
        ushort4 o;
        o.x = f2bf(v.x); o.y = f2bf(v.y); o.z = f2bf(v.z); o.w = f2bf(v.w);
        *reinterpret_cast<ushort4*>(xb + i) = o;
    } else if (b < 12500 + 128) {
        int gid = (b - 12500) * 256 + threadIdx.x;      // < 32768
        int r = gid & 7, lane = (gid >> 3) & 63, t = (gid >> 9) & 7, ks = gid >> 12;
        int k = ks * 32 + ((lane >> 4) << 3) + r;
        int n = t * 16 + (lane & 15);
        float v = (k < 128) ? Wl1[k * 128 + n] : Wr1[(k - 128) * 128 + n];
        ushort h = f2bf(v);
        b1h[gid] = h;
        b1l[gid] = f2bf(v - bf2f(h));
    } else {
        int gid = (b - 12628) * 256 + threadIdx.x;      // < 16384
        int r = gid & 7, lane = (gid >> 3) & 63, t = (gid >> 9) & 7, ks = gid >> 12;
        int k = ks * 32 + ((lane >> 4) << 3) + r;
        int col = t * 16 + (lane & 15);
        float v = (col < 64) ? Wl2[k * 64 + col] : Wr2[k * 64 + (col - 64)];
        ushort h = f2bf(v);
        b2h[gid] = h;
        b2l[gid] = f2bf(v - bf2f(h));
    }
}

// ------- layer-1 gather mean over bf16 x; writes hi/lo bf16 planes ------------
__global__ __launch_bounds__(256) void agg_mean_kernel(
    const ushort* __restrict__ xb, const int* __restrict__ off,
    const int* __restrict__ srcS, ushort* __restrict__ meanH,
    ushort* __restrict__ meanL) {
    int n = blockIdx.x * 4 + (threadIdx.x >> 6);
    if (n >= N_NODES) return;
    int lane = threadIdx.x & 63;
    int s0 = off[n], s1 = off[n + 1];
    float ax = 0.0f, ay = 0.0f;
    int k = s0;
    for (; k + 4 <= s1; k += 4) {
        int sa = srcS[k], sb = srcS[k + 1], sc = srcS[k + 2], sd = srcS[k + 3];
        uint va = *(const uint*)(xb + (size_t)sa * 128 + lane * 2);
        uint vb = *(const uint*)(xb + (size_t)sb * 128 + lane * 2);
        uint vc = *(const uint*)(xb + (size_t)sc * 128 + lane * 2);
        uint vd = *(const uint*)(xb + (size_t)sd * 128 + lane * 2);
        ax += bflo(va) + bflo(vb) + bflo(vc) + bflo(vd);
        ay += bfhi(va) + bfhi(vb) + bfhi(vc) + bfhi(vd);
    }
    for (; k < s1; ++k) {
        uint v = *(const uint*)(xb + (size_t)srcS[k] * 128 + lane * 2);
        ax += bflo(v);
        ay += bfhi(v);
    }
    float inv = (s1 > s0) ? 1.0f / (float)(s1 - s0) : 0.0f;
    float mx = ax * inv, my = ay * inv;
    ushort hx = f2bf(mx), hy = f2bf(my);
    ushort lx = f2bf(mx - bf2f(hx)), ly = f2bf(my - bf2f(hy));
    *(uint*)(meanH + (size_t)n * 128 + lane * 2) = (uint)hx | ((uint)hy << 16);
    *(uint*)(meanL + (size_t)n * 128 + lane * 2) = (uint)lx | ((uint)ly << 16);
}

// ------- fused MLP with block-shared double-buffered B staging ----------------
// 512 threads = 8 waves x 16 rows. Per ks: 16KB B slice (hi|lo) in LDS,
// staged T14-style (load early, ds_write late), one barrier per ks.
__global__ __launch_bounds__(512) void mlp_kernel(
    const ushort* __restrict__ meanH, const ushort* __restrict__ meanL,
    const ushort* __restrict__ xb,
    const ushort* __restrict__ b1h, const ushort* __restrict__ b1l,
    const float* __restrict__ b1,
    const ushort* __restrict__ b2h, const ushort* __restrict__ b2l,
    ushort* __restrict__ tb, ushort* __restrict__ ub) {
    __shared__ __align__(16) ushort Bbuf[2][8192];   // 2 x 16KB (hi 8KB | lo 8KB)
    __shared__ __align__(16) ushort hs[8][2048];     // 8 waves x 4KB h tile
    const int tid = threadIdx.x;
    const int w = tid >> 6, lane = tid & 63;
    const int lrow = lane & 15, kg = lane >> 4;
    int wid = blockIdx.x * 8 + w;
    if (wid > N_NODES / 16 - 1) wid = N_NODES / 16 - 1;   // clamp: dup work, same values
    const size_t r0 = (size_t)wid * 16;
    char* hw = (char*)&hs[w][0];
    const f32x4 z4 = {0.f, 0.f, 0.f, 0.f};

    // wave's staging source: 2KB of the 16KB slice {ph[ks] | pl[ks]}
#define STAGE_SRC(ph, pl, ks) \
    (((w < 4) ? (const char*)(ph) : (const char*)(pl)) + (ks) * 8192 + (w & 3) * 2048)

    // prologue: stage A-slice ks=0
    {
        const char* src = STAGE_SRC(b1h, b1l, 0);
        ushort8v s0v = *(const ushort8v*)(src + lane * 16);
        ushort8v s1v = *(const ushort8v*)(src + 1024 + lane * 16);
        ushort* dst = &Bbuf[0][0] + w * 1024;
        *(ushort8v*)(dst + lane * 8) = s0v;
        *(ushort8v*)(dst + 512 + lane * 8) = s1v;
    }
    __syncthreads();

    // ---- phase A: layer-1 GEMM ----
    f32x4 acc[8];
#pragma unroll
    for (int t = 0; t < 8; ++t) acc[t] = z4;
#pragma unroll
    for (int ks = 0; ks < 8; ++ks) {
        const int cur = ks & 1;
        // issue next-slice loads early (A ks+1, or W2 ks=0 after last)
        const char* nsrc = (ks < 7) ? STAGE_SRC(b1h, b1l, ks + 1)
                                    : STAGE_SRC(b2h, b2l, 0);
        ushort8v s0v = *(const ushort8v*)(nsrc + lane * 16);
        ushort8v s1v = *(const ushort8v*)(nsrc + 1024 + lane * 16);
        // A fragments
        bf16x8 aH, aL;
        if (ks < 4) {
            aH = *(const bf16x8*)(meanH + (r0 + lrow) * 128 + ks * 32 + kg * 8);
            aL = *(const bf16x8*)(meanL + (r0 + lrow) * 128 + ks * 32 + kg * 8);
        } else {
            aH = *(const bf16x8*)(xb + (r0 + lrow) * 128 + (ks - 4) * 32 + kg * 8);
        }
        const ushort* Bc = &Bbuf[cur][0];
#pragma unroll
        for (int t = 0; t < 8; ++t) {
            bf16x8 Bh = *(const bf16x8*)(Bc + (t * 64 + lane) * 8);
            bf16x8 Bl = *(const bf16x8*)(Bc + 4096 + (t * 64 + lane) * 8);
            acc[t] = __builtin_amdgcn_mfma_f32_16x16x32_bf16(aH, Bh, acc[t], 0, 0, 0);
            acc[t] = __builtin_amdgcn_mfma_f32_16x16x32_bf16(aH, Bl, acc[t], 0, 0, 0);
            if (ks < 4)
                acc[t] = __builtin_amdgcn_mfma_f32_16x16x32_bf16(aL, Bh, acc[t], 0, 0, 0);
        }
        // write staged slice late
        ushort* dst = &Bbuf[cur ^ 1][0] + w * 1024;
        *(ushort8v*)(dst + lane * 8) = s0v;
        *(ushort8v*)(dst + 512 + lane * 8) = s1v;
        __syncthreads();
    }

    // ---- epilogue A: bias + relu -> swizzled wave-private LDS h tile ----
#pragma unroll
    for (int t = 0; t < 8; ++t) {
        float bj = b1[t * 16 + lrow];
#pragma unroll
        for (int rg = 0; rg < 4; ++rg) {
            int row = kg * 4 + rg;
            int col2 = (t * 16 + lrow) * 2;
            int byte = row * 256 + (col2 ^ ((row & 7) << 4));
            *(ushort*)(hw + byte) = f2bf(fmaxf(acc[t][rg] + bj, 0.0f));
        }
    }

    // ---- phase B: layer-2 GEMM from LDS h ----
    f32x4 acc2[8];
#pragma unroll
    for (int t = 0; t < 8; ++t) acc2[t] = z4;
#pragma unroll
    for (int ks = 0; ks < 4; ++ks) {
        const int cur = ks & 1;   // parity continues from phase A (W2 ks0 in buf 0)
        ushort8v s0v, s1v;
        if (ks < 3) {
            const char* nsrc = STAGE_SRC(b2h, b2l, ks + 1);
            s0v = *(const ushort8v*)(nsrc + lane * 16);
            s1v = *(const ushort8v*)(nsrc + 1024 + lane * 16);
        }
        int byte = lrow * 256 + ((ks * 64 + kg * 16) ^ ((lrow & 7) << 4));
        bf16x8 aH = *(const bf16x8*)(hw + byte);
        const ushort* Bc = &Bbuf[cur][0];
#pragma unroll
        for (int t = 0; t < 8; ++t) {
            bf16x8 Bh = *(const bf16x8*)(Bc + (t * 64 + lane) * 8);
            bf16x8 Bl = *(const bf16x8*)(Bc + 4096 + (t * 64 + lane) * 8);
            acc2[t] = __builtin_amdgcn_mfma_f32_16x16x32_bf16(aH, Bh, acc2[t], 0, 0, 0);
            acc2[t] = __builtin_amdgcn_mfma_f32_16x16x32_bf16(aH, Bl, acc2[t], 0, 0, 0);
        }
        if (ks < 3) {
            ushort* dst = &Bbuf[cur ^ 1][0] + w * 1024;
            *(ushort8v*)(dst + lane * 8) = s0v;
            *(ushort8v*)(dst + 512 + lane * 8) = s1v;
        }
        __syncthreads();
    }
#undef STAGE_SRC

    // ---- epilogue B: write t|u ----
#pragma unroll
    for (int t = 0; t < 8; ++t) {
#pragma unroll
        for (int rg = 0; rg < 4; ++rg) {
            size_t row = r0 + kg * 4 + rg;
            int col = t * 16 + lrow;
            if (t < 4) tb[row * 64 + col] = f2bf(acc2[t][rg]);
            else       ub[row * 64 + (col - 64)] = f2bf(acc2[t][rg]);
        }
    }
}

// ------- layer-2 gather (bf16 t, chunk-4) + combine: z = mean(t)+u+b2 ---------
__global__ __launch_bounds__(256) void agg_z_kernel(
    const ushort* __restrict__ tb, const ushort* __restrict__ ub,
    const float* __restrict__ b2, const int* __restrict__ off,
    const int* __restrict__ srcS, ushort* __restrict__ zb) {
    int n = blockIdx.x * 8 + (threadIdx.x >> 5);   // 2 nodes per wave
    if (n >= N_NODES) return;
    int l = threadIdx.x & 31;                      // channels 2l, 2l+1
    int s0 = off[n], s1 = off[n + 1];
    float ax = 0.0f, ay = 0.0f;
    int k = s0;
    for (; k + 4 <= s1; k += 4) {
        int sa = srcS[k], sb = srcS[k + 1], sc = srcS[k + 2], sd = srcS[k + 3];
        uint va = *(const uint*)(tb + (size_t)sa * 64 + l * 2);
        uint vb = *(const uint*)(tb + (size_t)sb * 64 + l * 2);
        uint vc = *(const uint*)(tb + (size_t)sc * 64 + l * 2);
        uint vd = *(const uint*)(tb + (size_t)sd * 64 + l * 2);
        ax += bflo(va) + bflo(vb) + bflo(vc) + bflo(vd);
        ay += bfhi(va) + bfhi(vb) + bfhi(vc) + bfhi(vd);
    }
    for (; k < s1; ++k) {
        uint v = *(const uint*)(tb + (size_t)srcS[k] * 64 + l * 2);
        ax += bflo(v);
        ay += bfhi(v);
    }
    float inv = (s1 > s0) ? 1.0f / (float)(s1 - s0) : 0.0f;
    uint uu = *(const uint*)(ub + (size_t)n * 64 + l * 2);
    float zx = ax * inv + bflo(uu) + b2[l * 2];
    float zy = ay * inv + bfhi(uu) + b2[l * 2 + 1];
    uint pz = (uint)f2bf(zx) | ((uint)f2bf(zy) << 16);
    *(uint*)(zb + (size_t)n * 64 + l * 2) = pz;
}

// ---------------- decode over bf16 z ------------------------------------------
__global__ __launch_bounds__(256) void decode_kernel(
    const ushort* __restrict__ zb,
    const int* __restrict__ pos, const int* __restrict__ neg,
    float* __restrict__ out) {
    int t = blockIdx.x * 256 + threadIdx.x;
    int g = t >> 4;
    int lane = t & 15;
    if (g >= 2 * NEP) return;
    const int* ei;
    int e;
    float* o;
    if (g < NEP) { ei = pos; e = g; o = out; }
    else         { ei = neg; e = g - NEP; o = out + NEP; }
    int a  = ei[e];
    int bn = ei[NEP + e];
    ushort4 va = *reinterpret_cast<const ushort4*>(zb + (size_t)a  * 64 + lane * 4);
    ushort4 vb = *reinterpret_cast<const ushort4*>(zb + (size_t)bn * 64 + lane * 4);
    float s = bf2f(va.x) * bf2f(vb.x) + bf2f(va.y) * bf2f(vb.y)
            + bf2f(va.z) * bf2f(vb.z) + bf2f(va.w) * bf2f(vb.w);
    s += __shfl_xor(s, 1);
    s += __shfl_xor(s, 2);
    s += __shfl_xor(s, 4);
    s += __shfl_xor(s, 8);
    if (lane == 0) o[e] = s;
}

extern "C" void kernel_launch(void* const* d_in, const int* in_sizes, int n_in,
                              void* d_out, int out_size, void* d_ws, size_t ws_size,
                              hipStream_t stream) {
    const float* x    = (const float*)d_in[0];
    const int*   ei   = (const int*)d_in[1];
    const int*   pos  = (const int*)d_in[2];
    const int*   neg  = (const int*)d_in[3];
    const float* Wl1  = (const float*)d_in[4];
    const float* Wr1  = (const float*)d_in[5];
    const float* b1   = (const float*)d_in[6];
    const float* Wl2  = (const float*)d_in[7];
    const float* Wr2  = (const float*)d_in[8];
    const float* b2   = (const float*)d_in[9];
    float* out = (float*)d_out;

    const size_t HALF = (size_t)N_NODES * 128 * 2;   // 25.6 MB (one bf16 plane)
    const size_t QTR  = (size_t)N_NODES * 64 * 2;    // 12.8 MB
    char* ws = (char*)d_ws;
    ushort* xb    = (ushort*)ws;                     // N*128 bf16
    ushort* meanH = (ushort*)(ws + HALF);            // N*128 bf16
    ushort* meanL = (ushort*)(ws + 2 * HALF);        // N*128 bf16
    ushort* tb    = (ushort*)(ws + 3 * HALF);                 // N*64 bf16
    ushort* ub    = (ushort*)(ws + 3 * HALF + QTR);           // N*64 bf16
    ushort* zb    = (ushort*)(ws + 3 * HALF + 2 * QTR);       // N*64 bf16
    // ints + packed weights
    int* cnt  = (int*)(ws + 3 * HALF + 3 * QTR);
    int* off  = cnt + N_NODES;
    int* off2 = off + N_NODES + 1;
    int* srcS = off2 + N_NODES;
    int* sums = srcS + NE;
    ushort* b1h = (ushort*)(sums + 512);
    ushort* b1l = b1h + 32768;
    ushort* b2h = b1l + 32768;
    ushort* b2l = b2h + 16384;

    // ---- CSR build ----
    hipMemsetAsync(cnt, 0, N_NODES * sizeof(int), stream);
    hist_kernel <<<(NE + 255) / 256, 256, 0, stream>>>(ei, cnt);
    scan1_kernel<<<NBLK_SCAN, 256, 0, stream>>>(cnt, off, sums);
    scan2_kernel<<<1, 512, 0, stream>>>(sums);
    scan3_kernel<<<NBLK_SCAN, 256, 0, stream>>>(off, off2, sums);
    fill_kernel <<<(NE + 255) / 256, 256, 0, stream>>>(ei, off2, srcS);

    // ---- prep: x->bf16 + weight packing (one kernel) ----
    prep_kernel<<<12692, 256, 0, stream>>>(x, xb, Wl1, Wr1, b1h, b1l,
                                           Wl2, Wr2, b2h, b2l);

    // ---- layer 1 aggregate ----
    agg_mean_kernel<<<N_NODES / 4, 256, 0, stream>>>(xb, off, srcS, meanH, meanL);

    // ---- fused MLP (layer-1 GEMM + relu + layer-2 GEMM), LDS-shared B ----
    mlp_kernel<<<(N_NODES / 16 + 7) / 8, 512, 0, stream>>>(
        meanH, meanL, xb, b1h, b1l, b1, b2h, b2l, tb, ub);

    // ---- layer 2 aggregate + combine ----
    agg_z_kernel<<<(N_NODES + 7) / 8, 256, 0, stream>>>(tb, ub, b2, off, srcS, zb);

    // ---- decode ----
    decode_kernel<<<(2 * NEP * 16) / 256, 256, 0, stream>>>(zb, pos, neg, out);
}

// Round 9
// 176.186 us; speedup vs baseline: 3.0371x; 1.1514x over previous
//
#include <hip/hip_runtime.h>

#define N_NODES 100000
#define NE 500000
#define NEP 100000
#define NBLK_SCAN ((N_NODES + 255) / 256)   // 391

typedef short bf16x8 __attribute__((ext_vector_type(8)));
typedef float f32x4  __attribute__((ext_vector_type(4)));
typedef ushort ushort8v __attribute__((ext_vector_type(8)));

__device__ inline ushort f2bf(float f) {
    uint u = __builtin_bit_cast(uint, f);
    return (ushort)((u + 0x7FFFu + ((u >> 16) & 1u)) >> 16);   // RNE
}
__device__ inline float bf2f(ushort h) {
    uint u = ((uint)h) << 16;
    return __builtin_bit_cast(float, u);
}
__device__ inline float bflo(uint v) { return __builtin_bit_cast(float, v << 16); }
__device__ inline float bfhi(uint v) { return __builtin_bit_cast(float, v & 0xFFFF0000u); }

// ---------------- CSR build ---------------------------------------------------
__global__ __launch_bounds__(256) void hist_kernel(
    const int* __restrict__ ei, int* __restrict__ cnt) {
    int e = blockIdx.x * 256 + threadIdx.x;
    if (e >= NE) return;
    atomicAdd(&cnt[ei[NE + e]], 1);
}

__global__ __launch_bounds__(256) void scan1_kernel(
    const int* __restrict__ cnt, int* __restrict__ off, int* __restrict__ sums) {
    __shared__ int buf[256];
    int t = threadIdx.x;
    int i = blockIdx.x * 256 + t;
    int v = (i < N_NODES) ? cnt[i] : 0;
    buf[t] = v;
    __syncthreads();
#pragma unroll
    for (int d = 1; d < 256; d <<= 1) {
        int add = (t >= d) ? buf[t - d] : 0;
        __syncthreads();
        buf[t] += add;
        __syncthreads();
    }
    if (i < N_NODES) off[i] = buf[t] - v;
    if (t == 255) sums[blockIdx.x] = buf[255];
}

__global__ __launch_bounds__(512) void scan2_kernel(int* __restrict__ sums) {
    __shared__ int buf[512];
    int t = threadIdx.x;
    int v = (t < NBLK_SCAN) ? sums[t] : 0;
    buf[t] = v;
    __syncthreads();
#pragma unroll
    for (int d = 1; d < 512; d <<= 1) {
        int add = (t >= d) ? buf[t - d] : 0;
        __syncthreads();
        buf[t] += add;
        __syncthreads();
    }
    if (t < NBLK_SCAN) sums[t] = buf[t] - v;
}

__global__ __launch_bounds__(256) void scan3_kernel(
    int* __restrict__ off, int* __restrict__ off2, const int* __restrict__ sums) {
    int i = blockIdx.x * 256 + threadIdx.x;
    if (i >= N_NODES) return;
    int o = off[i] + sums[blockIdx.x];
    off[i] = o;
    off2[i] = o;
    if (i == 0) off[N_NODES] = NE;
}

__global__ __launch_bounds__(256) void fill_kernel(
    const int* __restrict__ ei, int* __restrict__ off2, int* __restrict__ srcS) {
    int e = blockIdx.x * 256 + threadIdx.x;
    if (e >= NE) return;
    int src = ei[e];
    int dst = ei[NE + e];
    int pos = atomicAdd(&off2[dst], 1);
    srcS[pos] = src;
}

// -------- prep: x->bf16 (blocks 0..12499), pack W1-hi, W2-hi ------------------
__global__ __launch_bounds__(256) void prep_kernel(
    const float* __restrict__ x, ushort* __restrict__ xb,
    const float* __restrict__ Wl1, const float* __restrict__ Wr1,
    ushort* __restrict__ b1h,
    const float* __restrict__ Wl2, const float* __restrict__ Wr2,
    ushort* __restrict__ b2h) {
    int b = blockIdx.x;
    if (b < 12500) {
        size_t i = ((size_t)b * 256 + threadIdx.x) * 4;
        float4 v = *reinterpret_cast<const float4*>(x + i);
        ushort4 o;
        o.x = f2bf(v.x); o.y = f2bf(v.y); o.z = f2bf(v.z); o.w = f2bf(v.w);
        *reinterpret_cast<ushort4*>(xb + i) = o;
    } else if (b < 12500 + 128) {
        int gid = (b - 12500) * 256 + threadIdx.x;      // < 32768
        int r = gid & 7, lane = (gid >> 3) & 63, t = (gid >> 9) & 7, ks = gid >> 12;
        int k = ks * 32 + ((lane >> 4) << 3) + r;
        int n = t * 16 + (lane & 15);
        float v = (k < 128) ? Wl1[k * 128 + n] : Wr1[(k - 128) * 128 + n];
        b1h[gid] = f2bf(v);
    } else {
        int gid = (b - 12628) * 256 + threadIdx.x;      // < 16384
        int r = gid & 7, lane = (gid >> 3) & 63, t = (gid >> 9) & 7, ks = gid >> 12;
        int k = ks * 32 + ((lane >> 4) << 3) + r;
        int col = t * 16 + (lane & 15);
        float v = (col < 64) ? Wl2[k * 64 + col] : Wr2[k * 64 + (col - 64)];
        b2h[gid] = f2bf(v);
    }
}

// ------- layer-1 gather mean over bf16 x; writes bf16 mean --------------------
__global__ __launch_bounds__(256) void agg_mean_kernel(
    const ushort* __restrict__ xb, const int* __restrict__ off,
    const int* __restrict__ srcS, ushort* __restrict__ meanH) {
    int n = blockIdx.x * 4 + (threadIdx.x >> 6);
    if (n >= N_NODES) return;
    int lane = threadIdx.x & 63;
    int s0 = off[n], s1 = off[n + 1];
    float ax = 0.0f, ay = 0.0f;
    int k = s0;
    for (; k + 4 <= s1; k += 4) {
        int sa = srcS[k], sb = srcS[k + 1], sc = srcS[k + 2], sd = srcS[k + 3];
        uint va = *(const uint*)(xb + (size_t)sa * 128 + lane * 2);
        uint vb = *(const uint*)(xb + (size_t)sb * 128 + lane * 2);
        uint vc = *(const uint*)(xb + (size_t)sc * 128 + lane * 2);
        uint vd = *(const uint*)(xb + (size_t)sd * 128 + lane * 2);
        ax += bflo(va) + bflo(vb) + bflo(vc) + bflo(vd);
        ay += bfhi(va) + bfhi(vb) + bfhi(vc) + bfhi(vd);
    }
    for (; k < s1; ++k) {
        uint v = *(const uint*)(xb + (size_t)srcS[k] * 128 + lane * 2);
        ax += bflo(v);
        ay += bfhi(v);
    }
    float inv = (s1 > s0) ? 1.0f / (float)(s1 - s0) : 0.0f;
    float mx = ax * inv, my = ay * inv;
    *(uint*)(meanH + (size_t)n * 128 + lane * 2) =
        (uint)f2bf(mx) | ((uint)f2bf(my) << 16);
}

// ------- fused MLP: stage W1+W2 hi once (96KB LDS), ONE barrier ---------------
// 512 threads = 8 waves x 16 rows. After barrier: waves fully independent.
// Phase A: 64 MFMA vs W1-LDS; h -> swizzled wave-private LDS; phase B: 32 MFMA.
__global__ __launch_bounds__(512) void mlp_kernel(
    const ushort* __restrict__ meanH, const ushort* __restrict__ xb,
    const ushort* __restrict__ b1h, const float* __restrict__ b1,
    const ushort* __restrict__ b2h,
    ushort* __restrict__ tb, ushort* __restrict__ ub) {
    __shared__ __align__(16) ushort Ws[49152];     // 96KB: W1 chunks [0,4096), W2 [4096,6144)
    __shared__ __align__(16) ushort hs[8][2048];   // 8 waves x 4KB h tile
    const int tid = threadIdx.x;
    const int w = tid >> 6, lane = tid & 63;
    const int lrow = lane & 15, kg = lane >> 4;
    int wid = blockIdx.x * 8 + w;
    if (wid > N_NODES / 16 - 1) wid = N_NODES / 16 - 1;   // clamp: dup work, same values
    const size_t r0 = (size_t)wid * 16;
    char* hw = (char*)&hs[w][0];
    const f32x4 z4 = {0.f, 0.f, 0.f, 0.f};

    // ---- stage all B once (6144 x 16B chunks) ----
    {
        const ushort8v* src1 = (const ushort8v*)b1h;
        const ushort8v* src2 = (const ushort8v*)b2h;
        ushort8v* dst = (ushort8v*)Ws;
#pragma unroll
        for (int i = 0; i < 12; ++i) {
            int j = tid + i * 512;
            dst[j] = (j < 4096) ? src1[j] : src2[j - 4096];
        }
    }
    __syncthreads();   // the only barrier

    // ---- phase A: layer-1 GEMM (K=256: mean | x) ----
    f32x4 acc[8];
#pragma unroll
    for (int t = 0; t < 8; ++t) acc[t] = z4;
#pragma unroll
    for (int ks = 0; ks < 8; ++ks) {
        bf16x8 aH = (ks < 4)
            ? *(const bf16x8*)(meanH + (r0 + lrow) * 128 + ks * 32 + kg * 8)
            : *(const bf16x8*)(xb + (r0 + lrow) * 128 + (ks - 4) * 32 + kg * 8);
#pragma unroll
        for (int t = 0; t < 8; ++t) {
            bf16x8 Bh = *(const bf16x8*)(Ws + (ks * 8 + t) * 512 + lane * 8);
            acc[t] = __builtin_amdgcn_mfma_f32_16x16x32_bf16(aH, Bh, acc[t], 0, 0, 0);
        }
    }

    // ---- epilogue A: bias + relu -> swizzled wave-private LDS h tile ----
#pragma unroll
    for (int t = 0; t < 8; ++t) {
        float bj = b1[t * 16 + lrow];
#pragma unroll
        for (int rg = 0; rg < 4; ++rg) {
            int row = kg * 4 + rg;
            int col2 = (t * 16 + lrow) * 2;
            int byte = row * 256 + (col2 ^ ((row & 7) << 4));
            *(ushort*)(hw + byte) = f2bf(fmaxf(acc[t][rg] + bj, 0.0f));
        }
    }

    // ---- phase B: layer-2 GEMM from LDS h (K=128) ----
    f32x4 acc2[8];
#pragma unroll
    for (int t = 0; t < 8; ++t) acc2[t] = z4;
#pragma unroll
    for (int ks = 0; ks < 4; ++ks) {
        int byte = lrow * 256 + ((ks * 64 + kg * 16) ^ ((lrow & 7) << 4));
        bf16x8 aH = *(const bf16x8*)(hw + byte);
#pragma unroll
        for (int t = 0; t < 8; ++t) {
            bf16x8 Bh = *(const bf16x8*)(Ws + (4096 + ks * 8 + t) * 512 / 1 + lane * 8 - 4096 * 512 + 4096 * 512);
            // (kept simple below)
            acc2[t] = __builtin_amdgcn_mfma_f32_16x16x32_bf16(
                *(const bf16x8*)(Ws + 32768 + (ks * 8 + t) * 512 + lane * 8),
                aH, acc2[t], 0, 0, 0) - acc2[t] + acc2[t];
            (void)Bh;
        }
    }
    // NOTE: the above expression pattern is wrong-order; recompute properly:
#pragma unroll
    for (int t = 0; t < 8; ++t) acc2[t] = z4;
#pragma unroll
    for (int ks = 0; ks < 4; ++ks) {
        int byte = lrow * 256 + ((ks * 64 + kg * 16) ^ ((lrow & 7) << 4));
        bf16x8 aH = *(const bf16x8*)(hw + byte);
#pragma unroll
        for (int t = 0; t < 8; ++t) {
            bf16x8 Bh = *(const bf16x8*)(Ws + 32768 + (ks * 8 + t) * 512 + lane * 8);
            acc2[t] = __builtin_amdgcn_mfma_f32_16x16x32_bf16(aH, Bh, acc2[t], 0, 0, 0);
        }
    }

    // ---- epilogue B: write t|u ----
#pragma unroll
    for (int t = 0; t < 8; ++t) {
#pragma unroll
        for (int rg = 0; rg < 4; ++rg) {
            size_t row = r0 + kg * 4 + rg;
            int col = t * 16 + lrow;
            if (t < 4) tb[row * 64 + col] = f2bf(acc2[t][rg]);
            else       ub[row * 64 + (col - 64)] = f2bf(acc2[t][rg]);
        }
    }
}

// ------- layer-2 gather (bf16 t, chunk-4) + combine: z = mean(t)+u+b2 ---------
__global__ __launch_bounds__(256) void agg_z_kernel(
    const ushort* __restrict__ tb, const ushort* __restrict__ ub,
    const float* __restrict__ b2, const int* __restrict__ off,
    const int* __restrict__ srcS, ushort* __restrict__ zb) {
    int n = blockIdx.x * 8 + (threadIdx.x >> 5);   // 2 nodes per wave
    if (n >= N_NODES) return;
    int l = threadIdx.x & 31;                      // channels 2l, 2l+1
    int s0 = off[n], s1 = off[n + 1];
    float ax = 0.0f, ay = 0.0f;
    int k = s0;
    for (; k + 4 <= s1; k += 4) {
        int sa = srcS[k], sb = srcS[k + 1], sc = srcS[k + 2], sd = srcS[k + 3];
        uint va = *(const uint*)(tb + (size_t)sa * 64 + l * 2);
        uint vb = *(const uint*)(tb + (size_t)sb * 64 + l * 2);
        uint vc = *(const uint*)(tb + (size_t)sc * 64 + l * 2);
        uint vd = *(const uint*)(tb + (size_t)sd * 64 + l * 2);
        ax += bflo(va) + bflo(vb) + bflo(vc) + bflo(vd);
        ay += bfhi(va) + bfhi(vb) + bfhi(vc) + bfhi(vd);
    }
    for (; k < s1; ++k) {
        uint v = *(const uint*)(tb + (size_t)srcS[k] * 64 + l * 2);
        ax += bflo(v);
        ay += bfhi(v);
    }
    float inv = (s1 > s0) ? 1.0f / (float)(s1 - s0) : 0.0f;
    uint uu = *(const uint*)(ub + (size_t)n * 64 + l * 2);
    float zx = ax * inv + bflo(uu) + b2[l * 2];
    float zy = ay * inv + bfhi(uu) + b2[l * 2 + 1];
    uint pz = (uint)f2bf(zx) | ((uint)f2bf(zy) << 16);
    *(uint*)(zb + (size_t)n * 64 + l * 2) = pz;
}

// ---------------- decode over bf16 z ------------------------------------------
__global__ __launch_bounds__(256) void decode_kernel(
    const ushort* __restrict__ zb,
    const int* __restrict__ pos, const int* __restrict__ neg,
    float* __restrict__ out) {
    int t = blockIdx.x * 256 + threadIdx.x;
    int g = t >> 4;
    int lane = t & 15;
    if (g >= 2 * NEP) return;
    const int* ei;
    int e;
    float* o;
    if (g < NEP) { ei = pos; e = g; o = out; }
    else         { ei = neg; e = g - NEP; o = out + NEP; }
    int a  = ei[e];
    int bn = ei[NEP + e];
    ushort4 va = *reinterpret_cast<const ushort4*>(zb + (size_t)a  * 64 + lane * 4);
    ushort4 vb = *reinterpret_cast<const ushort4*>(zb + (size_t)bn * 64 + lane * 4);
    float s = bf2f(va.x) * bf2f(vb.x) + bf2f(va.y) * bf2f(vb.y)
            + bf2f(va.z) * bf2f(vb.z) + bf2f(va.w) * bf2f(vb.w);
    s += __shfl_xor(s, 1);
    s += __shfl_xor(s, 2);
    s += __shfl_xor(s, 4);
    s += __shfl_xor(s, 8);
    if (lane == 0) o[e] = s;
}

extern "C" void kernel_launch(void* const* d_in, const int* in_sizes, int n_in,
                              void* d_out, int out_size, void* d_ws, size_t ws_size,
                              hipStream_t stream) {
    const float* x    = (const float*)d_in[0];
    const int*   ei   = (const int*)d_in[1];
    const int*   pos  = (const int*)d_in[2];
    const int*   neg  = (const int*)d_in[3];
    const float* Wl1  = (const float*)d_in[4];
    const float* Wr1  = (const float*)d_in[5];
    const float* b1   = (const float*)d_in[6];
    const float* Wl2  = (const float*)d_in[7];
    const float* Wr2  = (const float*)d_in[8];
    const float* b2   = (const float*)d_in[9];
    float* out = (float*)d_out;

    const size_t HALF = (size_t)N_NODES * 128 * 2;   // 25.6 MB (one bf16 plane)
    const size_t QTR  = (size_t)N_NODES * 64 * 2;    // 12.8 MB
    char* ws = (char*)d_ws;
    ushort* xb    = (ushort*)ws;                     // N*128 bf16
    ushort* meanH = (ushort*)(ws + HALF);            // N*128 bf16
    ushort* tb    = (ushort*)(ws + 2 * HALF);                 // N*64 bf16
    ushort* ub    = (ushort*)(ws + 2 * HALF + QTR);           // N*64 bf16
    ushort* zb    = (ushort*)(ws + 2 * HALF + 2 * QTR);       // N*64 bf16
    // ints + packed weights
    int* cnt  = (int*)(ws + 2 * HALF + 3 * QTR);
    int* off  = cnt + N_NODES;
    int* off2 = off + N_NODES + 1;
    int* srcS = off2 + N_NODES;
    int* sums = srcS + NE;
    ushort* b1h = (ushort*)(sums + 512);   // 32768 ushorts
    ushort* b2h = b1h + 32768;             // 16384 ushorts

    // ---- CSR build ----
    hipMemsetAsync(cnt, 0, N_NODES * sizeof(int), stream);
    hist_kernel <<<(NE + 255) / 256, 256, 0, stream>>>(ei, cnt);
    scan1_kernel<<<NBLK_SCAN, 256, 0, stream>>>(cnt, off, sums);
    scan2_kernel<<<1, 512, 0, stream>>>(sums);
    scan3_kernel<<<NBLK_SCAN, 256, 0, stream>>>(off, off2, sums);
    fill_kernel <<<(NE + 255) / 256, 256, 0, stream>>>(ei, off2, srcS);

    // ---- prep: x->bf16 + weight packing (hi planes only) ----
    prep_kernel<<<12692, 256, 0, stream>>>(x, xb, Wl1, Wr1, b1h, Wl2, Wr2, b2h);

    // ---- layer 1 aggregate ----
    agg_mean_kernel<<<N_NODES / 4, 256, 0, stream>>>(xb, off, srcS, meanH);

    // ---- fused MLP: stage-once LDS B, one barrier ----
    mlp_kernel<<<(N_NODES / 16 + 7) / 8, 512, 0, stream>>>(
        meanH, xb, b1h, b1, b2h, tb, ub);

    // ---- layer 2 aggregate + combine ----
    agg_z_kernel<<<(N_NODES + 7) / 8, 256, 0, stream>>>(tb, ub, b2, off, srcS, zb);

    // ---- decode ----
    decode_kernel<<<(2 * NEP * 16) / 256, 256, 0, stream>>>(zb, pos, neg, out);
}

// Round 10
// 170.072 us; speedup vs baseline: 3.1463x; 1.0359x over previous
//
#include <hip/hip_runtime.h>

#define N_NODES 100000
#define NE 500000
#define NEP 100000
#define NBLK_SCAN ((N_NODES + 255) / 256)   // 391

typedef short bf16x8 __attribute__((ext_vector_type(8)));
typedef float f32x4  __attribute__((ext_vector_type(4)));
typedef ushort ushort8v __attribute__((ext_vector_type(8)));

__device__ inline ushort f2bf(float f) {
    uint u = __builtin_bit_cast(uint, f);
    return (ushort)((u + 0x7FFFu + ((u >> 16) & 1u)) >> 16);   // RNE
}
__device__ inline float bf2f(ushort h) {
    uint u = ((uint)h) << 16;
    return __builtin_bit_cast(float, u);
}
__device__ inline float bflo(uint v) { return __builtin_bit_cast(float, v << 16); }
__device__ inline float bfhi(uint v) { return __builtin_bit_cast(float, v & 0xFFFF0000u); }

// ---------------- CSR build ---------------------------------------------------
__global__ __launch_bounds__(256) void hist_kernel(
    const int* __restrict__ ei, int* __restrict__ cnt) {
    int e = blockIdx.x * 256 + threadIdx.x;
    if (e >= NE) return;
    atomicAdd(&cnt[ei[NE + e]], 1);
}

__global__ __launch_bounds__(256) void scan1_kernel(
    const int* __restrict__ cnt, int* __restrict__ off, int* __restrict__ sums) {
    __shared__ int buf[256];
    int t = threadIdx.x;
    int i = blockIdx.x * 256 + t;
    int v = (i < N_NODES) ? cnt[i] : 0;
    buf[t] = v;
    __syncthreads();
#pragma unroll
    for (int d = 1; d < 256; d <<= 1) {
        int add = (t >= d) ? buf[t - d] : 0;
        __syncthreads();
        buf[t] += add;
        __syncthreads();
    }
    if (i < N_NODES) off[i] = buf[t] - v;
    if (t == 255) sums[blockIdx.x] = buf[255];
}

__global__ __launch_bounds__(512) void scan2_kernel(int* __restrict__ sums) {
    __shared__ int buf[512];
    int t = threadIdx.x;
    int v = (t < NBLK_SCAN) ? sums[t] : 0;
    buf[t] = v;
    __syncthreads();
#pragma unroll
    for (int d = 1; d < 512; d <<= 1) {
        int add = (t >= d) ? buf[t - d] : 0;
        __syncthreads();
        buf[t] += add;
        __syncthreads();
    }
    if (t < NBLK_SCAN) sums[t] = buf[t] - v;
}

__global__ __launch_bounds__(256) void scan3_kernel(
    int* __restrict__ off, int* __restrict__ off2, const int* __restrict__ sums) {
    int i = blockIdx.x * 256 + threadIdx.x;
    if (i >= N_NODES) return;
    int o = off[i] + sums[blockIdx.x];
    off[i] = o;
    off2[i] = o;
    if (i == 0) off[N_NODES] = NE;
}

__global__ __launch_bounds__(256) void fill_kernel(
    const int* __restrict__ ei, int* __restrict__ off2, int* __restrict__ srcS) {
    int e = blockIdx.x * 256 + threadIdx.x;
    if (e >= NE) return;
    int src = ei[e];
    int dst = ei[NE + e];
    int pos = atomicAdd(&off2[dst], 1);
    srcS[pos] = src;
}

// -------- prep: x->bf16 | pack W1-hi | pack W2-hi | zero cnt -------------------
__global__ __launch_bounds__(256) void prep_kernel(
    const float* __restrict__ x, ushort* __restrict__ xb,
    const float* __restrict__ Wl1, const float* __restrict__ Wr1,
    ushort* __restrict__ b1h,
    const float* __restrict__ Wl2, const float* __restrict__ Wr2,
    ushort* __restrict__ b2h, int* __restrict__ cnt) {
    int b = blockIdx.x;
    if (b < 12500) {
        size_t i = ((size_t)b * 256 + threadIdx.x) * 4;
        float4 v = *reinterpret_cast<const float4*>(x + i);
        ushort4 o;
        o.x = f2bf(v.x); o.y = f2bf(v.y); o.z = f2bf(v.z); o.w = f2bf(v.w);
        *reinterpret_cast<ushort4*>(xb + i) = o;
    } else if (b < 12500 + 128) {
        int gid = (b - 12500) * 256 + threadIdx.x;      // < 32768
        int r = gid & 7, lane = (gid >> 3) & 63, t = (gid >> 9) & 7, ks = gid >> 12;
        int k = ks * 32 + ((lane >> 4) << 3) + r;
        int n = t * 16 + (lane & 15);
        float v = (k < 128) ? Wl1[k * 128 + n] : Wr1[(k - 128) * 128 + n];
        b1h[gid] = f2bf(v);
    } else if (b < 12692) {
        int gid = (b - 12628) * 256 + threadIdx.x;      // < 16384
        int r = gid & 7, lane = (gid >> 3) & 63, t = (gid >> 9) & 7, ks = gid >> 12;
        int k = ks * 32 + ((lane >> 4) << 3) + r;
        int col = t * 16 + (lane & 15);
        float v = (col < 64) ? Wl2[k * 64 + col] : Wr2[k * 64 + (col - 64)];
        b2h[gid] = f2bf(v);
    } else {
        // zero cnt: 98 blocks x 256 threads x 4 ints (overshoot lands in off,
        // which scan1/scan3 rewrite afterwards)
        int i = ((b - 12692) * 256 + threadIdx.x) * 4;
        *reinterpret_cast<int4*>(cnt + i) = make_int4(0, 0, 0, 0);
    }
}

// ------- layer-1 gather mean over bf16 x; writes bf16 mean --------------------
__global__ __launch_bounds__(256) void agg_mean_kernel(
    const ushort* __restrict__ xb, const int* __restrict__ off,
    const int* __restrict__ srcS, ushort* __restrict__ meanH) {
    int n = blockIdx.x * 4 + (threadIdx.x >> 6);
    if (n >= N_NODES) return;
    int lane = threadIdx.x & 63;
    int s0 = off[n], s1 = off[n + 1];
    float ax = 0.0f, ay = 0.0f;
    int k = s0;
    for (; k + 4 <= s1; k += 4) {
        int sa = srcS[k], sb = srcS[k + 1], sc = srcS[k + 2], sd = srcS[k + 3];
        uint va = *(const uint*)(xb + (size_t)sa * 128 + lane * 2);
        uint vb = *(const uint*)(xb + (size_t)sb * 128 + lane * 2);
        uint vc = *(const uint*)(xb + (size_t)sc * 128 + lane * 2);
        uint vd = *(const uint*)(xb + (size_t)sd * 128 + lane * 2);
        ax += bflo(va) + bflo(vb) + bflo(vc) + bflo(vd);
        ay += bfhi(va) + bfhi(vb) + bfhi(vc) + bfhi(vd);
    }
    for (; k < s1; ++k) {
        uint v = *(const uint*)(xb + (size_t)srcS[k] * 128 + lane * 2);
        ax += bflo(v);
        ay += bfhi(v);
    }
    float inv = (s1 > s0) ? 1.0f / (float)(s1 - s0) : 0.0f;
    float mx = ax * inv, my = ay * inv;
    *(uint*)(meanH + (size_t)n * 128 + lane * 2) =
        (uint)f2bf(mx) | ((uint)f2bf(my) << 16);
}

// ------- fused MLP: stage W1+W2 hi once (96KB LDS), ONE barrier ---------------
// 512 threads = 8 waves x 16 rows. After barrier: waves fully independent.
__global__ __launch_bounds__(512) void mlp_kernel(
    const ushort* __restrict__ meanH, const ushort* __restrict__ xb,
    const ushort* __restrict__ b1h, const float* __restrict__ b1,
    const ushort* __restrict__ b2h,
    ushort* __restrict__ tb, ushort* __restrict__ ub) {
    __shared__ __align__(16) ushort Ws[49152];     // 96KB: W1 [0,32768), W2 [32768,49152)
    __shared__ __align__(16) ushort hs[8][2048];   // 8 waves x 4KB h tile
    const int tid = threadIdx.x;
    const int w = tid >> 6, lane = tid & 63;
    const int lrow = lane & 15, kg = lane >> 4;
    int wid = blockIdx.x * 8 + w;
    if (wid > N_NODES / 16 - 1) wid = N_NODES / 16 - 1;   // clamp: dup work, same values
    const size_t r0 = (size_t)wid * 16;
    char* hw = (char*)&hs[w][0];
    const f32x4 z4 = {0.f, 0.f, 0.f, 0.f};

    // ---- stage all B once (6144 x 16B chunks) ----
    {
        const ushort8v* src1 = (const ushort8v*)b1h;
        const ushort8v* src2 = (const ushort8v*)b2h;
        ushort8v* dst = (ushort8v*)Ws;
#pragma unroll
        for (int i = 0; i < 12; ++i) {
            int j = tid + i * 512;
            dst[j] = (j < 4096) ? src1[j] : src2[j - 4096];
        }
    }
    __syncthreads();   // the only barrier

    // ---- phase A: layer-1 GEMM (K=256: mean | x) ----
    f32x4 acc[8];
#pragma unroll
    for (int t = 0; t < 8; ++t) acc[t] = z4;
#pragma unroll
    for (int ks = 0; ks < 8; ++ks) {
        bf16x8 aH = (ks < 4)
            ? *(const bf16x8*)(meanH + (r0 + lrow) * 128 + ks * 32 + kg * 8)
            : *(const bf16x8*)(xb + (r0 + lrow) * 128 + (ks - 4) * 32 + kg * 8);
#pragma unroll
        for (int t = 0; t < 8; ++t) {
            bf16x8 Bh = *(const bf16x8*)(Ws + (ks * 8 + t) * 512 + lane * 8);
            acc[t] = __builtin_amdgcn_mfma_f32_16x16x32_bf16(aH, Bh, acc[t], 0, 0, 0);
        }
    }

    // ---- epilogue A: bias + relu -> swizzled wave-private LDS h tile ----
#pragma unroll
    for (int t = 0; t < 8; ++t) {
        float bj = b1[t * 16 + lrow];
#pragma unroll
        for (int rg = 0; rg < 4; ++rg) {
            int row = kg * 4 + rg;
            int col2 = (t * 16 + lrow) * 2;
            int byte = row * 256 + (col2 ^ ((row & 7) << 4));
            *(ushort*)(hw + byte) = f2bf(fmaxf(acc[t][rg] + bj, 0.0f));
        }
    }

    // ---- phase B: layer-2 GEMM from LDS h (K=128) ----
    f32x4 acc2[8];
#pragma unroll
    for (int t = 0; t < 8; ++t) acc2[t] = z4;
#pragma unroll
    for (int ks = 0; ks < 4; ++ks) {
        int byte = lrow * 256 + ((ks * 64 + kg * 16) ^ ((lrow & 7) << 4));
        bf16x8 aH = *(const bf16x8*)(hw + byte);
#pragma unroll
        for (int t = 0; t < 8; ++t) {
            bf16x8 Bh = *(const bf16x8*)(Ws + 32768 + (ks * 8 + t) * 512 + lane * 8);
            acc2[t] = __builtin_amdgcn_mfma_f32_16x16x32_bf16(aH, Bh, acc2[t], 0, 0, 0);
        }
    }

    // ---- epilogue B: write t|u ----
#pragma unroll
    for (int t = 0; t < 8; ++t) {
#pragma unroll
        for (int rg = 0; rg < 4; ++rg) {
            size_t row = r0 + kg * 4 + rg;
            int col = t * 16 + lrow;
            if (t < 4) tb[row * 64 + col] = f2bf(acc2[t][rg]);
            else       ub[row * 64 + (col - 64)] = f2bf(acc2[t][rg]);
        }
    }
}

// ------- layer-2 gather (bf16 t, chunk-4) + combine: z = mean(t)+u+b2 ---------
__global__ __launch_bounds__(256) void agg_z_kernel(
    const ushort* __restrict__ tb, const ushort* __restrict__ ub,
    const float* __restrict__ b2, const int* __restrict__ off,
    const int* __restrict__ srcS, ushort* __restrict__ zb) {
    int n = blockIdx.x * 8 + (threadIdx.x >> 5);   // 2 nodes per wave
    if (n >= N_NODES) return;
    int l = threadIdx.x & 31;                      // channels 2l, 2l+1
    int s0 = off[n], s1 = off[n + 1];
    float ax = 0.0f, ay = 0.0f;
    int k = s0;
    for (; k + 4 <= s1; k += 4) {
        int sa = srcS[k], sb = srcS[k + 1], sc = srcS[k + 2], sd = srcS[k + 3];
        uint va = *(const uint*)(tb + (size_t)sa * 64 + l * 2);
        uint vb = *(const uint*)(tb + (size_t)sb * 64 + l * 2);
        uint vc = *(const uint*)(tb + (size_t)sc * 64 + l * 2);
        uint vd = *(const uint*)(tb + (size_t)sd * 64 + l * 2);
        ax += bflo(va) + bflo(vb) + bflo(vc) + bflo(vd);
        ay += bfhi(va) + bfhi(vb) + bfhi(vc) + bfhi(vd);
    }
    for (; k < s1; ++k) {
        uint v = *(const uint*)(tb + (size_t)srcS[k] * 64 + l * 2);
        ax += bflo(v);
        ay += bfhi(v);
    }
    float inv = (s1 > s0) ? 1.0f / (float)(s1 - s0) : 0.0f;
    uint uu = *(const uint*)(ub + (size_t)n * 64 + l * 2);
    float zx = ax * inv + bflo(uu) + b2[l * 2];
    float zy = ay * inv + bfhi(uu) + b2[l * 2 + 1];
    uint pz = (uint)f2bf(zx) | ((uint)f2bf(zy) << 16);
    *(uint*)(zb + (size_t)n * 64 + l * 2) = pz;
}

// ---------------- decode over bf16 z ------------------------------------------
__global__ __launch_bounds__(256) void decode_kernel(
    const ushort* __restrict__ zb,
    const int* __restrict__ pos, const int* __restrict__ neg,
    float* __restrict__ out) {
    int t = blockIdx.x * 256 + threadIdx.x;
    int g = t >> 4;
    int lane = t & 15;
    if (g >= 2 * NEP) return;
    const int* ei;
    int e;
    float* o;
    if (g < NEP) { ei = pos; e = g; o = out; }
    else         { ei = neg; e = g - NEP; o = out + NEP; }
    int a  = ei[e];
    int bn = ei[NEP + e];
    ushort4 va = *reinterpret_cast<const ushort4*>(zb + (size_t)a  * 64 + lane * 4);
    ushort4 vb = *reinterpret_cast<const ushort4*>(zb + (size_t)bn * 64 + lane * 4);
    float s = bf2f(va.x) * bf2f(vb.x) + bf2f(va.y) * bf2f(vb.y)
            + bf2f(va.z) * bf2f(vb.z) + bf2f(va.w) * bf2f(vb.w);
    s += __shfl_xor(s, 1);
    s += __shfl_xor(s, 2);
    s += __shfl_xor(s, 4);
    s += __shfl_xor(s, 8);
    if (lane == 0) o[e] = s;
}

extern "C" void kernel_launch(void* const* d_in, const int* in_sizes, int n_in,
                              void* d_out, int out_size, void* d_ws, size_t ws_size,
                              hipStream_t stream) {
    const float* x    = (const float*)d_in[0];
    const int*   ei   = (const int*)d_in[1];
    const int*   pos  = (const int*)d_in[2];
    const int*   neg  = (const int*)d_in[3];
    const float* Wl1  = (const float*)d_in[4];
    const float* Wr1  = (const float*)d_in[5];
    const float* b1   = (const float*)d_in[6];
    const float* Wl2  = (const float*)d_in[7];
    const float* Wr2  = (const float*)d_in[8];
    const float* b2   = (const float*)d_in[9];
    float* out = (float*)d_out;

    const size_t HALF = (size_t)N_NODES * 128 * 2;   // 25.6 MB (one bf16 plane)
    const size_t QTR  = (size_t)N_NODES * 64 * 2;    // 12.8 MB
    char* ws = (char*)d_ws;
    ushort* xb    = (ushort*)ws;                     // N*128 bf16
    ushort* meanH = (ushort*)(ws + HALF);            // N*128 bf16
    ushort* tb    = (ushort*)(ws + 2 * HALF);                 // N*64 bf16
    ushort* ub    = (ushort*)(ws + 2 * HALF + QTR);           // N*64 bf16
    ushort* zb    = (ushort*)(ws + 2 * HALF + 2 * QTR);       // N*64 bf16
    // ints + packed weights
    int* cnt  = (int*)(ws + 2 * HALF + 3 * QTR);
    int* off  = cnt + N_NODES;
    int* off2 = off + N_NODES + 1;
    int* srcS = off2 + N_NODES;
    int* sums = srcS + NE;
    ushort* b1h = (ushort*)(sums + 512);   // 32768 ushorts
    ushort* b2h = b1h + 32768;             // 16384 ushorts

    // ---- prep: x->bf16 + weight packing + cnt zero (replaces hipMemsetAsync) ----
    prep_kernel<<<12790, 256, 0, stream>>>(x, xb, Wl1, Wr1, b1h, Wl2, Wr2, b2h, cnt);

    // ---- CSR build ----
    hist_kernel <<<(NE + 255) / 256, 256, 0, stream>>>(ei, cnt);
    scan1_kernel<<<NBLK_SCAN, 256, 0, stream>>>(cnt, off, sums);
    scan2_kernel<<<1, 512, 0, stream>>>(sums);
    scan3_kernel<<<NBLK_SCAN, 256, 0, stream>>>(off, off2, sums);
    fill_kernel <<<(NE + 255) / 256, 256, 0, stream>>>(ei, off2, srcS);

    // ---- layer 1 aggregate ----
    agg_mean_kernel<<<N_NODES / 4, 256, 0, stream>>>(xb, off, srcS, meanH);

    // ---- fused MLP: stage-once LDS B, one barrier ----
    mlp_kernel<<<(N_NODES / 16 + 7) / 8, 512, 0, stream>>>(
        meanH, xb, b1h, b1, b2h, tb, ub);

    // ---- layer 2 aggregate + combine ----
    agg_z_kernel<<<(N_NODES + 7) / 8, 256, 0, stream>>>(tb, ub, b2, off, srcS, zb);

    // ---- decode ----
    decode_kernel<<<(2 * NEP * 16) / 256, 256, 0, stream>>>(zb, pos, neg, out);
}

// Round 11
// 153.981 us; speedup vs baseline: 3.4750x; 1.1045x over previous
//
#include <hip/hip_runtime.h>

#define N_NODES 100000
#define NE 500000
#define NEP 100000
#define NBLK_SCAN ((N_NODES + 255) / 256)   // 391

typedef short bf16x8 __attribute__((ext_vector_type(8)));
typedef float f32x4  __attribute__((ext_vector_type(4)));
typedef ushort ushort8v __attribute__((ext_vector_type(8)));

__device__ inline ushort f2bf(float f) {
    uint u = __builtin_bit_cast(uint, f);
    return (ushort)((u + 0x7FFFu + ((u >> 16) & 1u)) >> 16);   // RNE
}
__device__ inline float bf2f(ushort h) {
    uint u = ((uint)h) << 16;
    return __builtin_bit_cast(float, u);
}
__device__ inline float bflo(uint v) { return __builtin_bit_cast(float, v << 16); }
__device__ inline float bfhi(uint v) { return __builtin_bit_cast(float, v & 0xFFFF0000u); }

// ---------------- CSR build ---------------------------------------------------
__global__ __launch_bounds__(256) void hist_kernel(
    const int* __restrict__ ei, int* __restrict__ cnt) {
    int e = blockIdx.x * 256 + threadIdx.x;
    if (e >= NE) return;
    atomicAdd(&cnt[ei[NE + e]], 1);
}

__global__ __launch_bounds__(256) void scan1_kernel(
    const int* __restrict__ cnt, int* __restrict__ off, int* __restrict__ sums) {
    __shared__ int buf[256];
    int t = threadIdx.x;
    int i = blockIdx.x * 256 + t;
    int v = (i < N_NODES) ? cnt[i] : 0;
    buf[t] = v;
    __syncthreads();
#pragma unroll
    for (int d = 1; d < 256; d <<= 1) {
        int add = (t >= d) ? buf[t - d] : 0;
        __syncthreads();
        buf[t] += add;
        __syncthreads();
    }
    if (i < N_NODES) off[i] = buf[t] - v;
    if (t == 255) sums[blockIdx.x] = buf[255];
}

__global__ __launch_bounds__(512) void scan2_kernel(int* __restrict__ sums) {
    __shared__ int buf[512];
    int t = threadIdx.x;
    int v = (t < NBLK_SCAN) ? sums[t] : 0;
    buf[t] = v;
    __syncthreads();
#pragma unroll
    for (int d = 1; d < 512; d <<= 1) {
        int add = (t >= d) ? buf[t - d] : 0;
        __syncthreads();
        buf[t] += add;
        __syncthreads();
    }
    if (t < NBLK_SCAN) sums[t] = buf[t] - v;
}

__global__ __launch_bounds__(256) void scan3_kernel(
    int* __restrict__ off, int* __restrict__ off2, const int* __restrict__ sums) {
    int i = blockIdx.x * 256 + threadIdx.x;
    if (i >= N_NODES) return;
    int o = off[i] + sums[blockIdx.x];
    off[i] = o;
    off2[i] = o;
    if (i == 0) off[N_NODES] = NE;
}

__global__ __launch_bounds__(256) void fill_kernel(
    const int* __restrict__ ei, int* __restrict__ off2, int* __restrict__ srcS) {
    int e = blockIdx.x * 256 + threadIdx.x;
    if (e >= NE) return;
    int src = ei[e];
    int dst = ei[NE + e];
    int pos = atomicAdd(&off2[dst], 1);
    srcS[pos] = src;
}

// -------- prep: x->bf16 | pack W1-hi | pack W2-hi | zero cnt -------------------
__global__ __launch_bounds__(256) void prep_kernel(
    const float* __restrict__ x, ushort* __restrict__ xb,
    const float* __restrict__ Wl1, const float* __restrict__ Wr1,
    ushort* __restrict__ b1h,
    const float* __restrict__ Wl2, const float* __restrict__ Wr2,
    ushort* __restrict__ b2h, int* __restrict__ cnt) {
    int b = blockIdx.x;
    if (b < 12500) {
        size_t i = ((size_t)b * 256 + threadIdx.x) * 4;
        float4 v = *reinterpret_cast<const float4*>(x + i);
        ushort4 o;
        o.x = f2bf(v.x); o.y = f2bf(v.y); o.z = f2bf(v.z); o.w = f2bf(v.w);
        *reinterpret_cast<ushort4*>(xb + i) = o;
    } else if (b < 12500 + 128) {
        int gid = (b - 12500) * 256 + threadIdx.x;      // < 32768
        int r = gid & 7, lane = (gid >> 3) & 63, t = (gid >> 9) & 7, ks = gid >> 12;
        int k = ks * 32 + ((lane >> 4) << 3) + r;
        int n = t * 16 + (lane & 15);
        float v = (k < 128) ? Wl1[k * 128 + n] : Wr1[(k - 128) * 128 + n];
        b1h[gid] = f2bf(v);
    } else if (b < 12692) {
        int gid = (b - 12628) * 256 + threadIdx.x;      // < 16384
        int r = gid & 7, lane = (gid >> 3) & 63, t = (gid >> 9) & 7, ks = gid >> 12;
        int k = ks * 32 + ((lane >> 4) << 3) + r;
        int col = t * 16 + (lane & 15);
        float v = (col < 64) ? Wl2[k * 64 + col] : Wr2[k * 64 + (col - 64)];
        b2h[gid] = f2bf(v);
    } else {
        // zero cnt: 98 blocks x 256 threads x 4 ints (overshoot lands in off,
        // which scan1/scan3 rewrite afterwards)
        int i = ((b - 12692) * 256 + threadIdx.x) * 4;
        *reinterpret_cast<int4*>(cnt + i) = make_int4(0, 0, 0, 0);
    }
}

// ------- layer-1 gather mean: 2 nodes/wave, 32 lanes/node, uint2 loads --------
__global__ __launch_bounds__(256) void agg_mean_kernel(
    const ushort* __restrict__ xb, const int* __restrict__ off,
    const int* __restrict__ srcS, ushort* __restrict__ meanH) {
    int n = blockIdx.x * 8 + (threadIdx.x >> 5);   // 8 nodes per 256-thr block
    if (n >= N_NODES) return;
    int l = threadIdx.x & 31;                      // channels 4l..4l+3
    int s0 = off[n], s1 = off[n + 1];
    float a0 = 0.f, a1 = 0.f, a2 = 0.f, a3 = 0.f;
    int k = s0;
    for (; k + 4 <= s1; k += 4) {
        int sa = srcS[k], sb = srcS[k + 1], sc = srcS[k + 2], sd = srcS[k + 3];
        uint2 va = *(const uint2*)(xb + (size_t)sa * 128 + l * 4);
        uint2 vb = *(const uint2*)(xb + (size_t)sb * 128 + l * 4);
        uint2 vc = *(const uint2*)(xb + (size_t)sc * 128 + l * 4);
        uint2 vd = *(const uint2*)(xb + (size_t)sd * 128 + l * 4);
        a0 += bflo(va.x) + bflo(vb.x) + bflo(vc.x) + bflo(vd.x);
        a1 += bfhi(va.x) + bfhi(vb.x) + bfhi(vc.x) + bfhi(vd.x);
        a2 += bflo(va.y) + bflo(vb.y) + bflo(vc.y) + bflo(vd.y);
        a3 += bfhi(va.y) + bfhi(vb.y) + bfhi(vc.y) + bfhi(vd.y);
    }
    for (; k < s1; ++k) {
        uint2 v = *(const uint2*)(xb + (size_t)srcS[k] * 128 + l * 4);
        a0 += bflo(v.x); a1 += bfhi(v.x);
        a2 += bflo(v.y); a3 += bfhi(v.y);
    }
    float inv = (s1 > s0) ? 1.0f / (float)(s1 - s0) : 0.0f;
    uint2 o;
    o.x = (uint)f2bf(a0 * inv) | ((uint)f2bf(a1 * inv) << 16);
    o.y = (uint)f2bf(a2 * inv) | ((uint)f2bf(a3 * inv) << 16);
    *(uint2*)(meanH + (size_t)n * 128 + l * 4) = o;
}

// ------- fused MLP: prefetch A-frags, stage W1+W2 hi once, ONE barrier --------
__global__ __launch_bounds__(512) void mlp_kernel(
    const ushort* __restrict__ meanH, const ushort* __restrict__ xb,
    const ushort* __restrict__ b1h, const float* __restrict__ b1,
    const ushort* __restrict__ b2h,
    ushort* __restrict__ tb, ushort* __restrict__ ub) {
    __shared__ __align__(16) ushort Ws[49152];     // 96KB: W1 [0,32768), W2 [32768,49152)
    __shared__ __align__(16) ushort hs[8][2048];   // 8 waves x 4KB h tile
    const int tid = threadIdx.x;
    const int w = tid >> 6, lane = tid & 63;
    const int lrow = lane & 15, kg = lane >> 4;
    int wid = blockIdx.x * 8 + w;
    if (wid > N_NODES / 16 - 1) wid = N_NODES / 16 - 1;   // clamp: dup work, same values
    const size_t r0 = (size_t)wid * 16;
    char* hw = (char*)&hs[w][0];
    const f32x4 z4 = {0.f, 0.f, 0.f, 0.f};

    // ---- T14: issue all 8 A-frag global loads BEFORE the LDS stage ----
    bf16x8 aF[8];
#pragma unroll
    for (int ks = 0; ks < 4; ++ks)
        aF[ks] = *(const bf16x8*)(meanH + (r0 + lrow) * 128 + ks * 32 + kg * 8);
#pragma unroll
    for (int ks = 0; ks < 4; ++ks)
        aF[4 + ks] = *(const bf16x8*)(xb + (r0 + lrow) * 128 + ks * 32 + kg * 8);

    // ---- stage all B once (6144 x 16B chunks) ----
    {
        const ushort8v* src1 = (const ushort8v*)b1h;
        const ushort8v* src2 = (const ushort8v*)b2h;
        ushort8v* dst = (ushort8v*)Ws;
#pragma unroll
        for (int i = 0; i < 12; ++i) {
            int j = tid + i * 512;
            dst[j] = (j < 4096) ? src1[j] : src2[j - 4096];
        }
    }
    __syncthreads();   // the only barrier

    // ---- phase A: layer-1 GEMM (K=256: mean | x), all A in registers ----
    f32x4 acc[8];
#pragma unroll
    for (int t = 0; t < 8; ++t) acc[t] = z4;
#pragma unroll
    for (int ks = 0; ks < 8; ++ks) {
#pragma unroll
        for (int t = 0; t < 8; ++t) {
            bf16x8 Bh = *(const bf16x8*)(Ws + (ks * 8 + t) * 512 + lane * 8);
            acc[t] = __builtin_amdgcn_mfma_f32_16x16x32_bf16(aF[ks], Bh, acc[t], 0, 0, 0);
        }
    }

    // ---- epilogue A: bias + relu -> swizzled wave-private LDS h tile ----
#pragma unroll
    for (int t = 0; t < 8; ++t) {
        float bj = b1[t * 16 + lrow];
#pragma unroll
        for (int rg = 0; rg < 4; ++rg) {
            int row = kg * 4 + rg;
            int col2 = (t * 16 + lrow) * 2;
            int byte = row * 256 + (col2 ^ ((row & 7) << 4));
            *(ushort*)(hw + byte) = f2bf(fmaxf(acc[t][rg] + bj, 0.0f));
        }
    }

    // ---- phase B: layer-2 GEMM from LDS h (K=128), h-frags prefetched ----
    bf16x8 hF[4];
#pragma unroll
    for (int ks = 0; ks < 4; ++ks) {
        int byte = lrow * 256 + ((ks * 64 + kg * 16) ^ ((lrow & 7) << 4));
        hF[ks] = *(const bf16x8*)(hw + byte);
    }
    f32x4 acc2[8];
#pragma unroll
    for (int t = 0; t < 8; ++t) acc2[t] = z4;
#pragma unroll
    for (int ks = 0; ks < 4; ++ks) {
#pragma unroll
        for (int t = 0; t < 8; ++t) {
            bf16x8 Bh = *(const bf16x8*)(Ws + 32768 + (ks * 8 + t) * 512 + lane * 8);
            acc2[t] = __builtin_amdgcn_mfma_f32_16x16x32_bf16(hF[ks], Bh, acc2[t], 0, 0, 0);
        }
    }

    // ---- epilogue B: write t|u ----
#pragma unroll
    for (int t = 0; t < 8; ++t) {
#pragma unroll
        for (int rg = 0; rg < 4; ++rg) {
            size_t row = r0 + kg * 4 + rg;
            int col = t * 16 + lrow;
            if (t < 4) tb[row * 64 + col] = f2bf(acc2[t][rg]);
            else       ub[row * 64 + (col - 64)] = f2bf(acc2[t][rg]);
        }
    }
}

// ------- layer-2 gather: 4 nodes/wave, 16 lanes/node, uint2 loads -------------
__global__ __launch_bounds__(256) void agg_z_kernel(
    const ushort* __restrict__ tb, const ushort* __restrict__ ub,
    const float* __restrict__ b2, const int* __restrict__ off,
    const int* __restrict__ srcS, ushort* __restrict__ zb) {
    int n = blockIdx.x * 16 + (threadIdx.x >> 4);   // 16 nodes per 256-thr block
    if (n >= N_NODES) return;
    int l = threadIdx.x & 15;                       // channels 4l..4l+3
    int s0 = off[n], s1 = off[n + 1];
    float a0 = 0.f, a1 = 0.f, a2 = 0.f, a3 = 0.f;
    int k = s0;
    for (; k + 4 <= s1; k += 4) {
        int sa = srcS[k], sb = srcS[k + 1], sc = srcS[k + 2], sd = srcS[k + 3];
        uint2 va = *(const uint2*)(tb + (size_t)sa * 64 + l * 4);
        uint2 vb = *(const uint2*)(tb + (size_t)sb * 64 + l * 4);
        uint2 vc = *(const uint2*)(tb + (size_t)sc * 64 + l * 4);
        uint2 vd = *(const uint2*)(tb + (size_t)sd * 64 + l * 4);
        a0 += bflo(va.x) + bflo(vb.x) + bflo(vc.x) + bflo(vd.x);
        a1 += bfhi(va.x) + bfhi(vb.x) + bfhi(vc.x) + bfhi(vd.x);
        a2 += bflo(va.y) + bflo(vb.y) + bflo(vc.y) + bflo(vd.y);
        a3 += bfhi(va.y) + bfhi(vb.y) + bfhi(vc.y) + bfhi(vd.y);
    }
    for (; k < s1; ++k) {
        uint2 v = *(const uint2*)(tb + (size_t)srcS[k] * 64 + l * 4);
        a0 += bflo(v.x); a1 += bfhi(v.x);
        a2 += bflo(v.y); a3 += bfhi(v.y);
    }
    float inv = (s1 > s0) ? 1.0f / (float)(s1 - s0) : 0.0f;
    uint2 uu = *(const uint2*)(ub + (size_t)n * 64 + l * 4);
    float z0 = a0 * inv + bflo(uu.x) + b2[l * 4 + 0];
    float z1 = a1 * inv + bfhi(uu.x) + b2[l * 4 + 1];
    float z2 = a2 * inv + bflo(uu.y) + b2[l * 4 + 2];
    float z3 = a3 * inv + bfhi(uu.y) + b2[l * 4 + 3];
    uint2 o;
    o.x = (uint)f2bf(z0) | ((uint)f2bf(z1) << 16);
    o.y = (uint)f2bf(z2) | ((uint)f2bf(z3) << 16);
    *(uint2*)(zb + (size_t)n * 64 + l * 4) = o;
}

// ---------------- decode over bf16 z ------------------------------------------
__global__ __launch_bounds__(256) void decode_kernel(
    const ushort* __restrict__ zb,
    const int* __restrict__ pos, const int* __restrict__ neg,
    float* __restrict__ out) {
    int t = blockIdx.x * 256 + threadIdx.x;
    int g = t >> 4;
    int lane = t & 15;
    if (g >= 2 * NEP) return;
    const int* ei;
    int e;
    float* o;
    if (g < NEP) { ei = pos; e = g; o = out; }
    else         { ei = neg; e = g - NEP; o = out + NEP; }
    int a  = ei[e];
    int bn = ei[NEP + e];
    ushort4 va = *reinterpret_cast<const ushort4*>(zb + (size_t)a  * 64 + lane * 4);
    ushort4 vb = *reinterpret_cast<const ushort4*>(zb + (size_t)bn * 64 + lane * 4);
    float s = bf2f(va.x) * bf2f(vb.x) + bf2f(va.y) * bf2f(vb.y)
            + bf2f(va.z) * bf2f(vb.z) + bf2f(va.w) * bf2f(vb.w);
    s += __shfl_xor(s, 1);
    s += __shfl_xor(s, 2);
    s += __shfl_xor(s, 4);
    s += __shfl_xor(s, 8);
    if (lane == 0) o[e] = s;
}

extern "C" void kernel_launch(void* const* d_in, const int* in_sizes, int n_in,
                              void* d_out, int out_size, void* d_ws, size_t ws_size,
                              hipStream_t stream) {
    const float* x    = (const float*)d_in[0];
    const int*   ei   = (const int*)d_in[1];
    const int*   pos  = (const int*)d_in[2];
    const int*   neg  = (const int*)d_in[3];
    const float* Wl1  = (const float*)d_in[4];
    const float* Wr1  = (const float*)d_in[5];
    const float* b1   = (const float*)d_in[6];
    const float* Wl2  = (const float*)d_in[7];
    const float* Wr2  = (const float*)d_in[8];
    const float* b2   = (const float*)d_in[9];
    float* out = (float*)d_out;

    const size_t HALF = (size_t)N_NODES * 128 * 2;   // 25.6 MB (one bf16 plane)
    const size_t QTR  = (size_t)N_NODES * 64 * 2;    // 12.8 MB
    char* ws = (char*)d_ws;
    ushort* xb    = (ushort*)ws;                     // N*128 bf16
    ushort* meanH = (ushort*)(ws + HALF);            // N*128 bf16
    ushort* tb    = (ushort*)(ws + 2 * HALF);                 // N*64 bf16
    ushort* ub    = (ushort*)(ws + 2 * HALF + QTR);           // N*64 bf16
    ushort* zb    = (ushort*)(ws + 2 * HALF + 2 * QTR);       // N*64 bf16
    // ints + packed weights
    int* cnt  = (int*)(ws + 2 * HALF + 3 * QTR);
    int* off  = cnt + N_NODES;
    int* off2 = off + N_NODES + 1;
    int* srcS = off2 + N_NODES;
    int* sums = srcS + NE;
    ushort* b1h = (ushort*)(sums + 512);   // 32768 ushorts
    ushort* b2h = b1h + 32768;             // 16384 ushorts

    // ---- prep: x->bf16 + weight packing + cnt zero ----
    prep_kernel<<<12790, 256, 0, stream>>>(x, xb, Wl1, Wr1, b1h, Wl2, Wr2, b2h, cnt);

    // ---- CSR build ----
    hist_kernel <<<(NE + 255) / 256, 256, 0, stream>>>(ei, cnt);
    scan1_kernel<<<NBLK_SCAN, 256, 0, stream>>>(cnt, off, sums);
    scan2_kernel<<<1, 512, 0, stream>>>(sums);
    scan3_kernel<<<NBLK_SCAN, 256, 0, stream>>>(off, off2, sums);
    fill_kernel <<<(NE + 255) / 256, 256, 0, stream>>>(ei, off2, srcS);

    // ---- layer 1 aggregate ----
    agg_mean_kernel<<<N_NODES / 8, 256, 0, stream>>>(xb, off, srcS, meanH);

    // ---- fused MLP: stage-once LDS B, one barrier ----
    mlp_kernel<<<(N_NODES / 16 + 7) / 8, 512, 0, stream>>>(
        meanH, xb, b1h, b1, b2h, tb, ub);

    // ---- layer 2 aggregate + combine ----
    agg_z_kernel<<<N_NODES / 16 + 1, 256, 0, stream>>>(tb, ub, b2, off, srcS, zb);

    // ---- decode ----
    decode_kernel<<<(2 * NEP * 16) / 256, 256, 0, stream>>>(zb, pos, neg, out);
}

// Round 13
// 146.272 us; speedup vs baseline: 3.6582x; 1.0527x over previous
//
#include <hip/hip_runtime.h>

#define N_NODES 100000
#define NE 500000
#define NEP 100000
#define NBLK_SCAN ((N_NODES + 255) / 256)   // 391

typedef short bf16x8 __attribute__((ext_vector_type(8)));
typedef float f32x4  __attribute__((ext_vector_type(4)));
typedef ushort ushort8v __attribute__((ext_vector_type(8)));

__device__ inline ushort f2bf(float f) {
    uint u = __builtin_bit_cast(uint, f);
    return (ushort)((u + 0x7FFFu + ((u >> 16) & 1u)) >> 16);   // RNE
}
__device__ inline float bf2f(ushort h) {
    uint u = ((uint)h) << 16;
    return __builtin_bit_cast(float, u);
}
__device__ inline float bflo(uint v) { return __builtin_bit_cast(float, v << 16); }
__device__ inline float bfhi(uint v) { return __builtin_bit_cast(float, v & 0xFFFF0000u); }

// ---------------- CSR build ---------------------------------------------------
__global__ __launch_bounds__(256) void hist_kernel(
    const int* __restrict__ ei, int* __restrict__ cnt) {
    int e = blockIdx.x * 256 + threadIdx.x;
    if (e >= NE) return;
    atomicAdd(&cnt[ei[NE + e]], 1);
}

__global__ __launch_bounds__(256) void scan1_kernel(
    const int* __restrict__ cnt, int* __restrict__ off, int* __restrict__ sums) {
    __shared__ int buf[256];
    int t = threadIdx.x;
    int i = blockIdx.x * 256 + t;
    int v = (i < N_NODES) ? cnt[i] : 0;
    buf[t] = v;
    __syncthreads();
#pragma unroll
    for (int d = 1; d < 256; d <<= 1) {
        int add = (t >= d) ? buf[t - d] : 0;
        __syncthreads();
        buf[t] += add;
        __syncthreads();
    }
    if (i < N_NODES) off[i] = buf[t] - v;
    if (t == 255) sums[blockIdx.x] = buf[255];
}

// merged scan2+scan3: each block reduces its own prefix of sums
__global__ __launch_bounds__(256) void scan23_kernel(
    int* __restrict__ off, int* __restrict__ off2, const int* __restrict__ sums) {
    __shared__ int red[256];
    int bid = blockIdx.x, t = threadIdx.x;
    int v = 0;
    if (t < bid) v += sums[t];
    if (t + 256 < bid) v += sums[t + 256];   // bid <= 390 < 512
    red[t] = v;
    __syncthreads();
#pragma unroll
    for (int d = 128; d > 0; d >>= 1) {
        if (t < d) red[t] += red[t + d];
        __syncthreads();
    }
    int pre = red[0];
    int i = bid * 256 + t;
    if (i < N_NODES) {
        int o = off[i] + pre;
        off[i] = o;
        off2[i] = o;
    }
    if (i == 0) off[N_NODES] = NE;
}

__global__ __launch_bounds__(256) void fill_kernel(
    const int* __restrict__ ei, int* __restrict__ off2, int* __restrict__ srcS) {
    int e = blockIdx.x * 256 + threadIdx.x;
    if (e >= NE) return;
    int src = ei[e];
    int dst = ei[NE + e];
    int pos = atomicAdd(&off2[dst], 1);
    srcS[pos] = src;
}

// -------- prep: x->bf16 | pack W1-hi | pack W2-hi | zero cnt -------------------
__global__ __launch_bounds__(256) void prep_kernel(
    const float* __restrict__ x, ushort* __restrict__ xb,
    const float* __restrict__ Wl1, const float* __restrict__ Wr1,
    ushort* __restrict__ b1h,
    const float* __restrict__ Wl2, const float* __restrict__ Wr2,
    ushort* __restrict__ b2h, int* __restrict__ cnt) {
    int b = blockIdx.x;
    if (b < 12500) {
        size_t i = ((size_t)b * 256 + threadIdx.x) * 4;
        float4 v = *reinterpret_cast<const float4*>(x + i);
        ushort4 o;
        o.x = f2bf(v.x); o.y = f2bf(v.y); o.z = f2bf(v.z); o.w = f2bf(v.w);
        *reinterpret_cast<ushort4*>(xb + i) = o;
    } else if (b < 12500 + 128) {
        int gid = (b - 12500) * 256 + threadIdx.x;      // < 32768
        int r = gid & 7, lane = (gid >> 3) & 63, t = (gid >> 9) & 7, ks = gid >> 12;
        int k = ks * 32 + ((lane >> 4) << 3) + r;
        int n = t * 16 + (lane & 15);
        float v = (k < 128) ? Wl1[k * 128 + n] : Wr1[(k - 128) * 128 + n];
        b1h[gid] = f2bf(v);
    } else if (b < 12692) {
        int gid = (b - 12628) * 256 + threadIdx.x;      // < 16384
        int r = gid & 7, lane = (gid >> 3) & 63, t = (gid >> 9) & 7, ks = gid >> 12;
        int k = ks * 32 + ((lane >> 4) << 3) + r;
        int col = t * 16 + (lane & 15);
        float v = (col < 64) ? Wl2[k * 64 + col] : Wr2[k * 64 + (col - 64)];
        b2h[gid] = f2bf(v);
    } else {
        // zero cnt: 98 blocks x 256 threads x 4 ints (overshoot lands in off,
        // which scan1/scan23 rewrite afterwards)
        int i = ((b - 12692) * 256 + threadIdx.x) * 4;
        *reinterpret_cast<int4*>(cnt + i) = make_int4(0, 0, 0, 0);
    }
}

// ------- layer-1 gather mean: 2 nodes/wave, 32 lanes/node, uint2 loads --------
__global__ __launch_bounds__(256) void agg_mean_kernel(
    const ushort* __restrict__ xb, const int* __restrict__ off,
    const int* __restrict__ srcS, ushort* __restrict__ meanH) {
    int n = blockIdx.x * 8 + (threadIdx.x >> 5);   // 8 nodes per 256-thr block
    if (n >= N_NODES) return;
    int l = threadIdx.x & 31;                      // channels 4l..4l+3
    int s0 = off[n], s1 = off[n + 1];
    float a0 = 0.f, a1 = 0.f, a2 = 0.f, a3 = 0.f;
    int k = s0;
    for (; k + 4 <= s1; k += 4) {
        int sa = srcS[k], sb = srcS[k + 1], sc = srcS[k + 2], sd = srcS[k + 3];
        uint2 va = *(const uint2*)(xb + (size_t)sa * 128 + l * 4);
        uint2 vb = *(const uint2*)(xb + (size_t)sb * 128 + l * 4);
        uint2 vc = *(const uint2*)(xb + (size_t)sc * 128 + l * 4);
        uint2 vd = *(const uint2*)(xb + (size_t)sd * 128 + l * 4);
        a0 += bflo(va.x) + bflo(vb.x) + bflo(vc.x) + bflo(vd.x);
        a1 += bfhi(va.x) + bfhi(vb.x) + bfhi(vc.x) + bfhi(vd.x);
        a2 += bflo(va.y) + bflo(vb.y) + bflo(vc.y) + bflo(vd.y);
        a3 += bfhi(va.y) + bfhi(vb.y) + bfhi(vc.y) + bfhi(vd.y);
    }
    for (; k < s1; ++k) {
        uint2 v = *(const uint2*)(xb + (size_t)srcS[k] * 128 + l * 4);
        a0 += bflo(v.x); a1 += bfhi(v.x);
        a2 += bflo(v.y); a3 += bfhi(v.y);
    }
    float inv = (s1 > s0) ? 1.0f / (float)(s1 - s0) : 0.0f;
    uint2 o;
    o.x = (uint)f2bf(a0 * inv) | ((uint)f2bf(a1 * inv) << 16);
    o.y = (uint)f2bf(a2 * inv) | ((uint)f2bf(a3 * inv) << 16);
    *(uint2*)(meanH + (size_t)n * 128 + l * 4) = o;
}

// ------- fused MLP: prefetch A-frags, stage W1+W2 hi once, ONE barrier --------
__global__ __launch_bounds__(512) void mlp_kernel(
    const ushort* __restrict__ meanH, const ushort* __restrict__ xb,
    const ushort* __restrict__ b1h, const float* __restrict__ b1,
    const ushort* __restrict__ b2h,
    ushort* __restrict__ tb, ushort* __restrict__ ub) {
    __shared__ __align__(16) ushort Ws[49152];     // 96KB: W1 [0,32768), W2 [32768,49152)
    __shared__ __align__(16) ushort hs[8][2048];   // 8 waves x 4KB h tile
    const int tid = threadIdx.x;
    const int w = tid >> 6, lane = tid & 63;
    const int lrow = lane & 15, kg = lane >> 4;
    int wid = blockIdx.x * 8 + w;
    if (wid > N_NODES / 16 - 1) wid = N_NODES / 16 - 1;   // clamp: dup work, same values
    const size_t r0 = (size_t)wid * 16;
    char* hw = (char*)&hs[w][0];
    const f32x4 z4 = {0.f, 0.f, 0.f, 0.f};

    // ---- T14: issue all 8 A-frag global loads BEFORE the LDS stage ----
    bf16x8 aF[8];
#pragma unroll
    for (int ks = 0; ks < 4; ++ks)
        aF[ks] = *(const bf16x8*)(meanH + (r0 + lrow) * 128 + ks * 32 + kg * 8);
#pragma unroll
    for (int ks = 0; ks < 4; ++ks)
        aF[4 + ks] = *(const bf16x8*)(xb + (r0 + lrow) * 128 + ks * 32 + kg * 8);

    // ---- stage all B once (6144 x 16B chunks) ----
    {
        const ushort8v* src1 = (const ushort8v*)b1h;
        const ushort8v* src2 = (const ushort8v*)b2h;
        ushort8v* dst = (ushort8v*)Ws;
#pragma unroll
        for (int i = 0; i < 12; ++i) {
            int j = tid + i * 512;
            dst[j] = (j < 4096) ? src1[j] : src2[j - 4096];
        }
    }
    __syncthreads();   // the only barrier

    // ---- phase A: layer-1 GEMM (K=256: mean | x), all A in registers ----
    f32x4 acc[8];
#pragma unroll
    for (int t = 0; t < 8; ++t) acc[t] = z4;
#pragma unroll
    for (int ks = 0; ks < 8; ++ks) {
#pragma unroll
        for (int t = 0; t < 8; ++t) {
            bf16x8 Bh = *(const bf16x8*)(Ws + (ks * 8 + t) * 512 + lane * 8);
            acc[t] = __builtin_amdgcn_mfma_f32_16x16x32_bf16(aF[ks], Bh, acc[t], 0, 0, 0);
        }
    }

    // ---- epilogue A: bias + relu -> swizzled wave-private LDS h tile ----
#pragma unroll
    for (int t = 0; t < 8; ++t) {
        float bj = b1[t * 16 + lrow];
#pragma unroll
        for (int rg = 0; rg < 4; ++rg) {
            int row = kg * 4 + rg;
            int col2 = (t * 16 + lrow) * 2;
            int byte = row * 256 + (col2 ^ ((row & 7) << 4));
            *(ushort*)(hw + byte) = f2bf(fmaxf(acc[t][rg] + bj, 0.0f));
        }
    }

    // ---- phase B: layer-2 GEMM from LDS h (K=128), h-frags prefetched ----
    bf16x8 hF[4];
#pragma unroll
    for (int ks = 0; ks < 4; ++ks) {
        int byte = lrow * 256 + ((ks * 64 + kg * 16) ^ ((lrow & 7) << 4));
        hF[ks] = *(const bf16x8*)(hw + byte);
    }
    f32x4 acc2[8];
#pragma unroll
    for (int t = 0; t < 8; ++t) acc2[t] = z4;
#pragma unroll
    for (int ks = 0; ks < 4; ++ks) {
#pragma unroll
        for (int t = 0; t < 8; ++t) {
            bf16x8 Bh = *(const bf16x8*)(Ws + 32768 + (ks * 8 + t) * 512 + lane * 8);
            acc2[t] = __builtin_amdgcn_mfma_f32_16x16x32_bf16(hF[ks], Bh, acc2[t], 0, 0, 0);
        }
    }

    // ---- epilogue B: write t|u ----
#pragma unroll
    for (int t = 0; t < 8; ++t) {
#pragma unroll
        for (int rg = 0; rg < 4; ++rg) {
            size_t row = r0 + kg * 4 + rg;
            int col = t * 16 + lrow;
            if (t < 4) tb[row * 64 + col] = f2bf(acc2[t][rg]);
            else       ub[row * 64 + (col - 64)] = f2bf(acc2[t][rg]);
        }
    }
}

// ------- layer-2 gather: 8 lanes/node, 16B loads ------------------------------
__global__ __launch_bounds__(256) void agg_z_kernel(
    const ushort* __restrict__ tb, const ushort* __restrict__ ub,
    const float* __restrict__ b2, const int* __restrict__ off,
    const int* __restrict__ srcS, ushort* __restrict__ zb) {
    int n = blockIdx.x * 32 + (threadIdx.x >> 3);   // 32 nodes per block
    if (n >= N_NODES) return;
    int l = threadIdx.x & 7;                        // channels 8l..8l+7
    int s0 = off[n], s1 = off[n + 1];
    float a0 = 0.f, a1 = 0.f, a2 = 0.f, a3 = 0.f;
    float a4 = 0.f, a5 = 0.f, a6 = 0.f, a7 = 0.f;
    int k = s0;
#define ACCZ(v)                                                   \
    { a0 += bflo((v).x); a1 += bfhi((v).x);                       \
      a2 += bflo((v).y); a3 += bfhi((v).y);                       \
      a4 += bflo((v).z); a5 += bfhi((v).z);                       \
      a6 += bflo((v).w); a7 += bfhi((v).w); }
    for (; k + 4 <= s1; k += 4) {
        int sa = srcS[k], sb = srcS[k + 1], sc = srcS[k + 2], sd = srcS[k + 3];
        uint4 va = *(const uint4*)(tb + (size_t)sa * 64 + l * 8);
        uint4 vb = *(const uint4*)(tb + (size_t)sb * 64 + l * 8);
        uint4 vc = *(const uint4*)(tb + (size_t)sc * 64 + l * 8);
        uint4 vd = *(const uint4*)(tb + (size_t)sd * 64 + l * 8);
        ACCZ(va) ACCZ(vb) ACCZ(vc) ACCZ(vd)
    }
    for (; k < s1; ++k) {
        uint4 v = *(const uint4*)(tb + (size_t)srcS[k] * 64 + l * 8);
        ACCZ(v)
    }
#undef ACCZ
    float inv = (s1 > s0) ? 1.0f / (float)(s1 - s0) : 0.0f;
    uint4 uu = *(const uint4*)(ub + (size_t)n * 64 + l * 8);
    const float* bp = b2 + l * 8;
    uint4 o;
    o.x = (uint)f2bf(a0 * inv + bflo(uu.x) + bp[0]) | ((uint)f2bf(a1 * inv + bfhi(uu.x) + bp[1]) << 16);
    o.y = (uint)f2bf(a2 * inv + bflo(uu.y) + bp[2]) | ((uint)f2bf(a3 * inv + bfhi(uu.y) + bp[3]) << 16);
    o.z = (uint)f2bf(a4 * inv + bflo(uu.z) + bp[4]) | ((uint)f2bf(a5 * inv + bfhi(uu.z) + bp[5]) << 16);
    o.w = (uint)f2bf(a6 * inv + bflo(uu.w) + bp[6]) | ((uint)f2bf(a7 * inv + bfhi(uu.w) + bp[7]) << 16);
    *(uint4*)(zb + (size_t)n * 64 + l * 8) = o;
}

// ---------------- decode over bf16 z: 8 lanes/edge ----------------------------
__global__ __launch_bounds__(256) void decode_kernel(
    const ushort* __restrict__ zb,
    const int* __restrict__ pos, const int* __restrict__ neg,
    float* __restrict__ out) {
    int t = blockIdx.x * 256 + threadIdx.x;
    int g = t >> 3;
    int lane = t & 7;
    if (g >= 2 * NEP) return;
    const int* ei;
    int e;
    float* o;
    if (g < NEP) { ei = pos; e = g; o = out; }
    else         { ei = neg; e = g - NEP; o = out + NEP; }
    int a  = ei[e];
    int bn = ei[NEP + e];
    uint4 va = *reinterpret_cast<const uint4*>(zb + (size_t)a  * 64 + lane * 8);
    uint4 vb = *reinterpret_cast<const uint4*>(zb + (size_t)bn * 64 + lane * 8);
    float s = bflo(va.x) * bflo(vb.x) + bfhi(va.x) * bfhi(vb.x)
            + bflo(va.y) * bflo(vb.y) + bfhi(va.y) * bfhi(vb.y)
            + bflo(va.z) * bflo(vb.z) + bfhi(va.z) * bfhi(vb.z)
            + bflo(va.w) * bflo(vb.w) + bfhi(va.w) * bfhi(vb.w);
    s += __shfl_xor(s, 1);
    s += __shfl_xor(s, 2);
    s += __shfl_xor(s, 4);
    if (lane == 0) o[e] = s;
}

extern "C" void kernel_launch(void* const* d_in, const int* in_sizes, int n_in,
                              void* d_out, int out_size, void* d_ws, size_t ws_size,
                              hipStream_t stream) {
    const float* x    = (const float*)d_in[0];
    const int*   ei   = (const int*)d_in[1];
    const int*   pos  = (const int*)d_in[2];
    const int*   neg  = (const int*)d_in[3];
    const float* Wl1  = (const float*)d_in[4];
    const float* Wr1  = (const float*)d_in[5];
    const float* b1   = (const float*)d_in[6];
    const float* Wl2  = (const float*)d_in[7];
    const float* Wr2  = (const float*)d_in[8];
    const float* b2   = (const float*)d_in[9];
    float* out = (float*)d_out;

    const size_t HALF = (size_t)N_NODES * 128 * 2;   // 25.6 MB (one bf16 plane)
    const size_t QTR  = (size_t)N_NODES * 64 * 2;    // 12.8 MB
    char* ws = (char*)d_ws;
    ushort* xb    = (ushort*)ws;                     // N*128 bf16
    ushort* meanH = (ushort*)(ws + HALF);            // N*128 bf16
    ushort* tb    = (ushort*)(ws + 2 * HALF);                 // N*64 bf16
    ushort* ub    = (ushort*)(ws + 2 * HALF + QTR);           // N*64 bf16
    ushort* zb    = (ushort*)(ws + 2 * HALF + 2 * QTR);       // N*64 bf16
    // ints + packed weights
    int* cnt  = (int*)(ws + 2 * HALF + 3 * QTR);
    int* off  = cnt + N_NODES;
    int* off2 = off + N_NODES + 1;
    int* srcS = off2 + N_NODES;
    int* sums = srcS + NE;
    ushort* b1h = (ushort*)(sums + 512);   // 32768 ushorts
    ushort* b2h = b1h + 32768;             // 16384 ushorts

    // ---- prep: x->bf16 + weight packing + cnt zero ----
    prep_kernel<<<12790, 256, 0, stream>>>(x, xb, Wl1, Wr1, b1h, Wl2, Wr2, b2h, cnt);

    // ---- CSR build ----
    hist_kernel <<<(NE + 255) / 256, 256, 0, stream>>>(ei, cnt);
    scan1_kernel<<<NBLK_SCAN, 256, 0, stream>>>(cnt, off, sums);
    scan23_kernel<<<NBLK_SCAN, 256, 0, stream>>>(off, off2, sums);
    fill_kernel <<<(NE + 255) / 256, 256, 0, stream>>>(ei, off2, srcS);

    // ---- layer 1 aggregate ----
    agg_mean_kernel<<<N_NODES / 8, 256, 0, stream>>>(xb, off, srcS, meanH);

    // ---- fused MLP: stage-once LDS B, one barrier ----
    mlp_kernel<<<(N_NODES / 16 + 7) / 8, 512, 0, stream>>>(
        meanH, xb, b1h, b1, b2h, tb, ub);

    // ---- layer 2 aggregate + combine ----
    agg_z_kernel<<<N_NODES / 32 + 1, 256, 0, stream>>>(tb, ub, b2, off, srcS, zb);

    // ---- decode ----
    decode_kernel<<<(2 * NEP * 8 + 255) / 256, 256, 0, stream>>>(zb, pos, neg, out);
}

// Round 14
// 142.438 us; speedup vs baseline: 3.7566x; 1.0269x over previous
//
#include <hip/hip_runtime.h>

#define N_NODES 100000
#define NE 500000
#define NEP 100000
#define NBLK_SCAN ((N_NODES + 255) / 256)   // 391

typedef short bf16x8 __attribute__((ext_vector_type(8)));
typedef float f32x4  __attribute__((ext_vector_type(4)));
typedef ushort ushort8v __attribute__((ext_vector_type(8)));

__device__ inline ushort f2bf(float f) {
    uint u = __builtin_bit_cast(uint, f);
    return (ushort)((u + 0x7FFFu + ((u >> 16) & 1u)) >> 16);   // RNE
}
__device__ inline float bf2f(ushort h) {
    uint u = ((uint)h) << 16;
    return __builtin_bit_cast(float, u);
}
__device__ inline float bflo(uint v) { return __builtin_bit_cast(float, v << 16); }
__device__ inline float bfhi(uint v) { return __builtin_bit_cast(float, v & 0xFFFF0000u); }

// ---------------- CSR build ---------------------------------------------------
__global__ __launch_bounds__(256) void hist_kernel(
    const int* __restrict__ ei, int* __restrict__ cnt) {
    int e = blockIdx.x * 256 + threadIdx.x;
    if (e >= NE) return;
    atomicAdd(&cnt[ei[NE + e]], 1);
}

__global__ __launch_bounds__(256) void scan1_kernel(
    const int* __restrict__ cnt, int* __restrict__ off, int* __restrict__ sums) {
    __shared__ int buf[256];
    int t = threadIdx.x;
    int i = blockIdx.x * 256 + t;
    int v = (i < N_NODES) ? cnt[i] : 0;
    buf[t] = v;
    __syncthreads();
#pragma unroll
    for (int d = 1; d < 256; d <<= 1) {
        int add = (t >= d) ? buf[t - d] : 0;
        __syncthreads();
        buf[t] += add;
        __syncthreads();
    }
    if (i < N_NODES) off[i] = buf[t] - v;
    if (t == 255) sums[blockIdx.x] = buf[255];
}

// merged scan2+scan3: each block reduces its own prefix of sums
__global__ __launch_bounds__(256) void scan23_kernel(
    int* __restrict__ off, int* __restrict__ off2, const int* __restrict__ sums) {
    __shared__ int red[256];
    int bid = blockIdx.x, t = threadIdx.x;
    int v = 0;
    if (t < bid) v += sums[t];
    if (t + 256 < bid) v += sums[t + 256];   // bid <= 390 < 512
    red[t] = v;
    __syncthreads();
#pragma unroll
    for (int d = 128; d > 0; d >>= 1) {
        if (t < d) red[t] += red[t + d];
        __syncthreads();
    }
    int pre = red[0];
    int i = bid * 256 + t;
    if (i < N_NODES) {
        int o = off[i] + pre;
        off[i] = o;
        off2[i] = o;
    }
    if (i == 0) off[N_NODES] = NE;
}

__global__ __launch_bounds__(256) void fill_kernel(
    const int* __restrict__ ei, int* __restrict__ off2, int* __restrict__ srcS) {
    int e = blockIdx.x * 256 + threadIdx.x;
    if (e >= NE) return;
    int src = ei[e];
    int dst = ei[NE + e];
    int pos = atomicAdd(&off2[dst], 1);
    srcS[pos] = src;
}

// -------- prep: x->bf16 | pack W1-hi | pack W2-hi | zero cnt -------------------
__global__ __launch_bounds__(256) void prep_kernel(
    const float* __restrict__ x, ushort* __restrict__ xb,
    const float* __restrict__ Wl1, const float* __restrict__ Wr1,
    ushort* __restrict__ b1h,
    const float* __restrict__ Wl2, const float* __restrict__ Wr2,
    ushort* __restrict__ b2h, int* __restrict__ cnt) {
    int b = blockIdx.x;
    if (b < 12500) {
        size_t i = ((size_t)b * 256 + threadIdx.x) * 4;
        float4 v = *reinterpret_cast<const float4*>(x + i);
        ushort4 o;
        o.x = f2bf(v.x); o.y = f2bf(v.y); o.z = f2bf(v.z); o.w = f2bf(v.w);
        *reinterpret_cast<ushort4*>(xb + i) = o;
    } else if (b < 12500 + 128) {
        int gid = (b - 12500) * 256 + threadIdx.x;      // < 32768
        int r = gid & 7, lane = (gid >> 3) & 63, t = (gid >> 9) & 7, ks = gid >> 12;
        int k = ks * 32 + ((lane >> 4) << 3) + r;
        int n = t * 16 + (lane & 15);
        float v = (k < 128) ? Wl1[k * 128 + n] : Wr1[(k - 128) * 128 + n];
        b1h[gid] = f2bf(v);
    } else if (b < 12692) {
        int gid = (b - 12628) * 256 + threadIdx.x;      // < 16384
        int r = gid & 7, lane = (gid >> 3) & 63, t = (gid >> 9) & 7, ks = gid >> 12;
        int k = ks * 32 + ((lane >> 4) << 3) + r;
        int col = t * 16 + (lane & 15);
        float v = (col < 64) ? Wl2[k * 64 + col] : Wr2[k * 64 + (col - 64)];
        b2h[gid] = f2bf(v);
    } else {
        // zero cnt: 98 blocks x 256 threads x 4 ints (overshoot lands in off,
        // which scan1/scan23 rewrite afterwards)
        int i = ((b - 12692) * 256 + threadIdx.x) * 4;
        *reinterpret_cast<int4*>(cnt + i) = make_int4(0, 0, 0, 0);
    }
}

// ------- layer-1 gather mean: 16 lanes/node, uint4 (16B) loads ----------------
// 16 nodes per 256-thread block -> 4 independent node-streams per wave.
__global__ __launch_bounds__(256) void agg_mean_kernel(
    const ushort* __restrict__ xb, const int* __restrict__ off,
    const int* __restrict__ srcS, ushort* __restrict__ meanH) {
    int n = blockIdx.x * 16 + (threadIdx.x >> 4);   // 100000/16 = 6250 exact
    int l = threadIdx.x & 15;                       // channels 8l..8l+7
    int s0 = off[n], s1 = off[n + 1];
    float a0 = 0.f, a1 = 0.f, a2 = 0.f, a3 = 0.f;
    float a4 = 0.f, a5 = 0.f, a6 = 0.f, a7 = 0.f;
    int k = s0;
#define ACCM(v)                                                   \
    { a0 += bflo((v).x); a1 += bfhi((v).x);                       \
      a2 += bflo((v).y); a3 += bfhi((v).y);                       \
      a4 += bflo((v).z); a5 += bfhi((v).z);                       \
      a6 += bflo((v).w); a7 += bfhi((v).w); }
    for (; k + 4 <= s1; k += 4) {
        int sa = srcS[k], sb = srcS[k + 1], sc = srcS[k + 2], sd = srcS[k + 3];
        uint4 va = *(const uint4*)(xb + (size_t)sa * 128 + l * 8);
        uint4 vb = *(const uint4*)(xb + (size_t)sb * 128 + l * 8);
        uint4 vc = *(const uint4*)(xb + (size_t)sc * 128 + l * 8);
        uint4 vd = *(const uint4*)(xb + (size_t)sd * 128 + l * 8);
        ACCM(va) ACCM(vb) ACCM(vc) ACCM(vd)
    }
    for (; k < s1; ++k) {
        uint4 v = *(const uint4*)(xb + (size_t)srcS[k] * 128 + l * 8);
        ACCM(v)
    }
#undef ACCM
    float inv = (s1 > s0) ? 1.0f / (float)(s1 - s0) : 0.0f;
    uint4 o;
    o.x = (uint)f2bf(a0 * inv) | ((uint)f2bf(a1 * inv) << 16);
    o.y = (uint)f2bf(a2 * inv) | ((uint)f2bf(a3 * inv) << 16);
    o.z = (uint)f2bf(a4 * inv) | ((uint)f2bf(a5 * inv) << 16);
    o.w = (uint)f2bf(a6 * inv) | ((uint)f2bf(a7 * inv) << 16);
    *(uint4*)(meanH + (size_t)n * 128 + l * 8) = o;
}

// ------- fused MLP: prefetch A-frags, stage W1+W2 hi once, ONE barrier --------
__global__ __launch_bounds__(512) void mlp_kernel(
    const ushort* __restrict__ meanH, const ushort* __restrict__ xb,
    const ushort* __restrict__ b1h, const float* __restrict__ b1,
    const ushort* __restrict__ b2h,
    ushort* __restrict__ tb, ushort* __restrict__ ub) {
    __shared__ __align__(16) ushort Ws[49152];     // 96KB: W1 [0,32768), W2 [32768,49152)
    __shared__ __align__(16) ushort hs[8][2048];   // 8 waves x 4KB h tile
    const int tid = threadIdx.x;
    const int w = tid >> 6, lane = tid & 63;
    const int lrow = lane & 15, kg = lane >> 4;
    int wid = blockIdx.x * 8 + w;
    if (wid > N_NODES / 16 - 1) wid = N_NODES / 16 - 1;   // clamp: dup work, same values
    const size_t r0 = (size_t)wid * 16;
    char* hw = (char*)&hs[w][0];
    const f32x4 z4 = {0.f, 0.f, 0.f, 0.f};

    // ---- T14: issue all 8 A-frag global loads BEFORE the LDS stage ----
    bf16x8 aF[8];
#pragma unroll
    for (int ks = 0; ks < 4; ++ks)
        aF[ks] = *(const bf16x8*)(meanH + (r0 + lrow) * 128 + ks * 32 + kg * 8);
#pragma unroll
    for (int ks = 0; ks < 4; ++ks)
        aF[4 + ks] = *(const bf16x8*)(xb + (r0 + lrow) * 128 + ks * 32 + kg * 8);

    // ---- stage all B once (6144 x 16B chunks) ----
    {
        const ushort8v* src1 = (const ushort8v*)b1h;
        const ushort8v* src2 = (const ushort8v*)b2h;
        ushort8v* dst = (ushort8v*)Ws;
#pragma unroll
        for (int i = 0; i < 12; ++i) {
            int j = tid + i * 512;
            dst[j] = (j < 4096) ? src1[j] : src2[j - 4096];
        }
    }
    __syncthreads();   // the only barrier

    // ---- phase A: layer-1 GEMM (K=256: mean | x), all A in registers ----
    f32x4 acc[8];
#pragma unroll
    for (int t = 0; t < 8; ++t) acc[t] = z4;
#pragma unroll
    for (int ks = 0; ks < 8; ++ks) {
#pragma unroll
        for (int t = 0; t < 8; ++t) {
            bf16x8 Bh = *(const bf16x8*)(Ws + (ks * 8 + t) * 512 + lane * 8);
            acc[t] = __builtin_amdgcn_mfma_f32_16x16x32_bf16(aF[ks], Bh, acc[t], 0, 0, 0);
        }
    }

    // ---- epilogue A: bias + relu -> swizzled wave-private LDS h tile ----
#pragma unroll
    for (int t = 0; t < 8; ++t) {
        float bj = b1[t * 16 + lrow];
#pragma unroll
        for (int rg = 0; rg < 4; ++rg) {
            int row = kg * 4 + rg;
            int col2 = (t * 16 + lrow) * 2;
            int byte = row * 256 + (col2 ^ ((row & 7) << 4));
            *(ushort*)(hw + byte) = f2bf(fmaxf(acc[t][rg] + bj, 0.0f));
        }
    }

    // ---- phase B: layer-2 GEMM from LDS h (K=128), h-frags prefetched ----
    bf16x8 hF[4];
#pragma unroll
    for (int ks = 0; ks < 4; ++ks) {
        int byte = lrow * 256 + ((ks * 64 + kg * 16) ^ ((lrow & 7) << 4));
        hF[ks] = *(const bf16x8*)(hw + byte);
    }
    f32x4 acc2[8];
#pragma unroll
    for (int t = 0; t < 8; ++t) acc2[t] = z4;
#pragma unroll
    for (int ks = 0; ks < 4; ++ks) {
#pragma unroll
        for (int t = 0; t < 8; ++t) {
            bf16x8 Bh = *(const bf16x8*)(Ws + 32768 + (ks * 8 + t) * 512 + lane * 8);
            acc2[t] = __builtin_amdgcn_mfma_f32_16x16x32_bf16(hF[ks], Bh, acc2[t], 0, 0, 0);
        }
    }

    // ---- epilogue B: write t|u ----
#pragma unroll
    for (int t = 0; t < 8; ++t) {
#pragma unroll
        for (int rg = 0; rg < 4; ++rg) {
            size_t row = r0 + kg * 4 + rg;
            int col = t * 16 + lrow;
            if (t < 4) tb[row * 64 + col] = f2bf(acc2[t][rg]);
            else       ub[row * 64 + (col - 64)] = f2bf(acc2[t][rg]);
        }
    }
}

// ------- layer-2 gather: 8 lanes/node, 16B loads ------------------------------
__global__ __launch_bounds__(256) void agg_z_kernel(
    const ushort* __restrict__ tb, const ushort* __restrict__ ub,
    const float* __restrict__ b2, const int* __restrict__ off,
    const int* __restrict__ srcS, ushort* __restrict__ zb) {
    int n = blockIdx.x * 32 + (threadIdx.x >> 3);   // 32 nodes per block
    if (n >= N_NODES) return;
    int l = threadIdx.x & 7;                        // channels 8l..8l+7
    int s0 = off[n], s1 = off[n + 1];
    float a0 = 0.f, a1 = 0.f, a2 = 0.f, a3 = 0.f;
    float a4 = 0.f, a5 = 0.f, a6 = 0.f, a7 = 0.f;
    int k = s0;
#define ACCZ(v)                                                   \
    { a0 += bflo((v).x); a1 += bfhi((v).x);                       \
      a2 += bflo((v).y); a3 += bfhi((v).y);                       \
      a4 += bflo((v).z); a5 += bfhi((v).z);                       \
      a6 += bflo((v).w); a7 += bfhi((v).w); }
    for (; k + 4 <= s1; k += 4) {
        int sa = srcS[k], sb = srcS[k + 1], sc = srcS[k + 2], sd = srcS[k + 3];
        uint4 va = *(const uint4*)(tb + (size_t)sa * 64 + l * 8);
        uint4 vb = *(const uint4*)(tb + (size_t)sb * 64 + l * 8);
        uint4 vc = *(const uint4*)(tb + (size_t)sc * 64 + l * 8);
        uint4 vd = *(const uint4*)(tb + (size_t)sd * 64 + l * 8);
        ACCZ(va) ACCZ(vb) ACCZ(vc) ACCZ(vd)
    }
    for (; k < s1; ++k) {
        uint4 v = *(const uint4*)(tb + (size_t)srcS[k] * 64 + l * 8);
        ACCZ(v)
    }
#undef ACCZ
    float inv = (s1 > s0) ? 1.0f / (float)(s1 - s0) : 0.0f;
    uint4 uu = *(const uint4*)(ub + (size_t)n * 64 + l * 8);
    const float* bp = b2 + l * 8;
    uint4 o;
    o.x = (uint)f2bf(a0 * inv + bflo(uu.x) + bp[0]) | ((uint)f2bf(a1 * inv + bfhi(uu.x) + bp[1]) << 16);
    o.y = (uint)f2bf(a2 * inv + bflo(uu.y) + bp[2]) | ((uint)f2bf(a3 * inv + bfhi(uu.y) + bp[3]) << 16);
    o.z = (uint)f2bf(a4 * inv + bflo(uu.z) + bp[4]) | ((uint)f2bf(a5 * inv + bfhi(uu.z) + bp[5]) << 16);
    o.w = (uint)f2bf(a6 * inv + bflo(uu.w) + bp[6]) | ((uint)f2bf(a7 * inv + bfhi(uu.w) + bp[7]) << 16);
    *(uint4*)(zb + (size_t)n * 64 + l * 8) = o;
}

// ---------------- decode over bf16 z: 8 lanes/edge ----------------------------
__global__ __launch_bounds__(256) void decode_kernel(
    const ushort* __restrict__ zb,
    const int* __restrict__ pos, const int* __restrict__ neg,
    float* __restrict__ out) {
    int t = blockIdx.x * 256 + threadIdx.x;
    int g = t >> 3;
    int lane = t & 7;
    if (g >= 2 * NEP) return;
    const int* ei;
    int e;
    float* o;
    if (g < NEP) { ei = pos; e = g; o = out; }
    else         { ei = neg; e = g - NEP; o = out + NEP; }
    int a  = ei[e];
    int bn = ei[NEP + e];
    uint4 va = *reinterpret_cast<const uint4*>(zb + (size_t)a  * 64 + lane * 8);
    uint4 vb = *reinterpret_cast<const uint4*>(zb + (size_t)bn * 64 + lane * 8);
    float s = bflo(va.x) * bflo(vb.x) + bfhi(va.x) * bfhi(vb.x)
            + bflo(va.y) * bflo(vb.y) + bfhi(va.y) * bfhi(vb.y)
            + bflo(va.z) * bflo(vb.z) + bfhi(va.z) * bfhi(vb.z)
            + bflo(va.w) * bflo(vb.w) + bfhi(va.w) * bfhi(vb.w);
    s += __shfl_xor(s, 1);
    s += __shfl_xor(s, 2);
    s += __shfl_xor(s, 4);
    if (lane == 0) o[e] = s;
}

extern "C" void kernel_launch(void* const* d_in, const int* in_sizes, int n_in,
                              void* d_out, int out_size, void* d_ws, size_t ws_size,
                              hipStream_t stream) {
    const float* x    = (const float*)d_in[0];
    const int*   ei   = (const int*)d_in[1];
    const int*   pos  = (const int*)d_in[2];
    const int*   neg  = (const int*)d_in[3];
    const float* Wl1  = (const float*)d_in[4];
    const float* Wr1  = (const float*)d_in[5];
    const float* b1   = (const float*)d_in[6];
    const float* Wl2  = (const float*)d_in[7];
    const float* Wr2  = (const float*)d_in[8];
    const float* b2   = (const float*)d_in[9];
    float* out = (float*)d_out;

    const size_t HALF = (size_t)N_NODES * 128 * 2;   // 25.6 MB (one bf16 plane)
    const size_t QTR  = (size_t)N_NODES * 64 * 2;    // 12.8 MB
    char* ws = (char*)d_ws;
    ushort* xb    = (ushort*)ws;                     // N*128 bf16
    ushort* meanH = (ushort*)(ws + HALF);            // N*128 bf16
    ushort* tb    = (ushort*)(ws + 2 * HALF);                 // N*64 bf16
    ushort* ub    = (ushort*)(ws + 2 * HALF + QTR);           // N*64 bf16
    ushort* zb    = (ushort*)(ws + 2 * HALF + 2 * QTR);       // N*64 bf16
    // ints + packed weights
    int* cnt  = (int*)(ws + 2 * HALF + 3 * QTR);
    int* off  = cnt + N_NODES;
    int* off2 = off + N_NODES + 1;
    int* srcS = off2 + N_NODES;
    int* sums = srcS + NE;
    ushort* b1h = (ushort*)(sums + 512);   // 32768 ushorts
    ushort* b2h = b1h + 32768;             // 16384 ushorts

    // ---- prep: x->bf16 + weight packing + cnt zero ----
    prep_kernel<<<12790, 256, 0, stream>>>(x, xb, Wl1, Wr1, b1h, Wl2, Wr2, b2h, cnt);

    // ---- CSR build ----
    hist_kernel <<<(NE + 255) / 256, 256, 0, stream>>>(ei, cnt);
    scan1_kernel<<<NBLK_SCAN, 256, 0, stream>>>(cnt, off, sums);
    scan23_kernel<<<NBLK_SCAN, 256, 0, stream>>>(off, off2, sums);
    fill_kernel <<<(NE + 255) / 256, 256, 0, stream>>>(ei, off2, srcS);

    // ---- layer 1 aggregate ----
    agg_mean_kernel<<<N_NODES / 16, 256, 0, stream>>>(xb, off, srcS, meanH);

    // ---- fused MLP: stage-once LDS B, one barrier ----
    mlp_kernel<<<(N_NODES / 16 + 7) / 8, 512, 0, stream>>>(
        meanH, xb, b1h, b1, b2h, tb, ub);

    // ---- layer 2 aggregate + combine ----
    agg_z_kernel<<<N_NODES / 32 + 1, 256, 0, stream>>>(tb, ub, b2, off, srcS, zb);

    // ---- decode ----
    decode_kernel<<<(2 * NEP * 8 + 255) / 256, 256, 0, stream>>>(zb, pos, neg, out);
}